// Round 9
// baseline (677.718 us; speedup 1.0000x reference)
//
#include <hip/hip_runtime.h>
#include <hip/hip_bf16.h>

#define NN 4608
#define BG 48
#define NPG 96
#define DD 512
#define XDIM 16
#define EREAL 147456
#define NLAYER 6
#define NK 262144     // 512*512
#define TRIU 4656     // 96*97/2

typedef __hip_bfloat16 bf16;
typedef short short8 __attribute__((ext_vector_type(8)));
typedef short short4v __attribute__((ext_vector_type(4)));
typedef float f32x4 __attribute__((ext_vector_type(4)));

// bf16 bits (as short) -> float: shift left 16
__device__ __forceinline__ float s2f(short s) {
  return __uint_as_float(((unsigned int)(unsigned short)s) << 16);
}
__device__ __forceinline__ short f2bs(float f) {
  bf16 h = __float2bfloat16(f);
  short s;
  __builtin_memcpy(&s, &h, 2);
  return s;
}

// ---------- weight transpose + bf16 convert; also zero counts & statsAll ----------
__global__ __launch_bounds__(256) void k_wt(const float* __restrict__ wl,
                                            const float* __restrict__ wr,
                                            const float* __restrict__ cg,
                                            const float* __restrict__ lin,
                                            bf16* __restrict__ Wt,
                                            int* __restrict__ counts,
                                            float* __restrict__ statsAll) {
  if (blockIdx.z == 0) {
    int id = (blockIdx.y * 16 + blockIdx.x) * 256 + threadIdx.x;
    if (id < NN) counts[id] = 0;
    if (id < 5 * 32) statsAll[id] = 0.f;
  }
  __shared__ float tile[32][33];
  int z = blockIdx.z;
  const float* src = (z < 6) ? wl + (size_t)z * NK
                   : (z < 12) ? wr + (size_t)(z - 6) * NK
                   : (z == 12) ? cg : lin;
  bf16* dst = Wt + (size_t)z * NK;
  int c = threadIdx.x & 31;
  int r0 = threadIdx.x >> 5;  // 0..7
  int bx = blockIdx.x * 32, by = blockIdx.y * 32;
#pragma unroll
  for (int i = 0; i < 4; i++) {
    int r = r0 + i * 8;
    tile[r][c] = src[(size_t)(by + r) * 512 + bx + c];  // [k][n]
  }
  __syncthreads();
#pragma unroll
  for (int i = 0; i < 4; i++) {
    int r = r0 + i * 8;  // n within tile
    dst[(size_t)(bx + r) * 512 + by + c] = __float2bfloat16(tile[c][r]);
  }
}

// ---------- x projection + edge histogram + cloud edge params ----------
__global__ void k_xproj(const float* __restrict__ x, const float* __restrict__ w,
                        const float* __restrict__ b, const int* __restrict__ ei,
                        const float* __restrict__ xyz, float* __restrict__ h,
                        bf16* __restrict__ h_bf, int* __restrict__ counts,
                        float* __restrict__ ep) {
  int i = blockIdx.x * blockDim.x + threadIdx.x;
  if (i >= NN * DD) return;
  if (i < EREAL) atomicAdd(&counts[ei[EREAL + i]], 1);
  if (i < NN * NPG) {
    int n = i / NPG, e = i - n * NPG;
    int p = n % NPG;
    if (e < NPG - p) {
      int g = n / NPG;
      int slot = g * TRIU + p * NPG - (p * (p - 1)) / 2 + e;
      int j = n + e;
      float dx = xyz[n * 3] - xyz[j * 3];
      float dy = xyz[n * 3 + 1] - xyz[j * 3 + 1];
      float dz = xyz[n * 3 + 2] - xyz[j * 3 + 2];
      float sq = dx * dx + dy * dy + dz * dz;
      float dist = (sq > 0.f) ? sqrtf(sq) : 0.f;
      float4 v;
      v.x = dx; v.y = dy; v.z = dz; v.w = __expf(-dist);
      *(float4*)&ep[(size_t)slot * 4] = v;
    }
  }
  int n = i >> 9, d = i & 511;
  float acc = b[d];
#pragma unroll
  for (int k = 0; k < XDIM; k++) acc += x[n * XDIM + k] * w[k * DD + d];
  h[i] = acc;
  h_bf[i] = __float2bfloat16(acc);
}

// ---------- edge sort (counting sort by dst; self loops handled in gat_edge) ----------
__global__ void k_scan(const int* __restrict__ counts, int* offsets, int* cursor) {
  __shared__ int part[256];
  __shared__ int pre[256];
  int t = threadIdx.x;
  int base = t * 18;  // 4608/256
  int s = 0;
#pragma unroll
  for (int i = 0; i < 18; i++) s += counts[base + i];
  part[t] = s;
  __syncthreads();
  if (t == 0) {
    int r = 0;
    for (int i = 0; i < 256; i++) { pre[i] = r; r += part[i]; }
  }
  __syncthreads();
  int run = pre[t];
#pragma unroll
  for (int i = 0; i < 18; i++) {
    offsets[base + i] = run;
    cursor[base + i] = run;
    run += counts[base + i];
  }
  if (t == 0) offsets[NN] = EREAL;
}
__global__ void k_scatter(const int* __restrict__ ei, int* cursor, int* ssrc) {
  int e = blockIdx.x * blockDim.x + threadIdx.x;
  if (e < EREAL) {
    int s = ei[e], d = ei[EREAL + e];
    int pos = atomicAdd(&cursor[d], 1);
    ssrc[pos] = s;
  }
}

// ---------- MFMA GEMM: C[4608,512] = A[4608,512] @ Wt^T + bias ----------
// A either bf16 (Abf) or fp32 (Afp) with fused graph-LN+relu (statsIn != null).
// BM=128 BN=64 BK=32, 4 waves. blockIdx.z picks slot 0/1 (B/bias/out).
__global__ __launch_bounds__(256) void k_gemm(
    const float* __restrict__ Afp, const bf16* __restrict__ Abf,
    const bf16* __restrict__ B0, const bf16* __restrict__ B1,
    const float* __restrict__ bias0, const float* __restrict__ bias1,
    float* __restrict__ C0, float* __restrict__ C1,
    bf16* __restrict__ Cb0, bf16* __restrict__ Cb1,
    const float* __restrict__ statsIn,
    const float* __restrict__ lng, const float* __restrict__ lnb,
    float* __restrict__ zptr, int zn) {
  if (zptr && blockIdx.x == 0 && blockIdx.y == 0 && blockIdx.z == 0) {
    for (int i = threadIdx.x; i < zn; i += 256) zptr[i] = 0.f;
  }
  __shared__ __align__(16) bf16 As[128 * 40];
  __shared__ __align__(16) bf16 Bs[64 * 40];
  const bf16* B = blockIdx.z ? B1 : B0;
  const float* bias = blockIdx.z ? bias1 : bias0;
  float* C = blockIdx.z ? C1 : C0;
  bf16* Cb = blockIdx.z ? Cb1 : Cb0;
  int tid = threadIdx.x;
  int m0 = blockIdx.x * 128, n0 = blockIdx.y * 64;
  int lane = tid & 63, wid = tid >> 6;
  int mh = (wid >> 1) * 64, nh = (wid & 1) * 32;
  int l15 = lane & 15, quad = lane >> 4;

  float mu = 0.f, inv = 1.f;
  if (statsIn) {
    float s = 0.f, ss = 0.f;
#pragma unroll
    for (int i = 0; i < 16; i++) { s += statsIn[i]; ss += statsIn[16 + i]; }
    const float invM = 1.f / ((float)NN * (float)DD);
    mu = s * invM;
    float var = ss * invM - mu * mu;
    float sd = sqrtf(fmaxf(var, 0.f));
    inv = 1.f / (sd + 1e-5f);
  }

  f32x4 acc[4][2];
#pragma unroll
  for (int mt = 0; mt < 4; mt++)
#pragma unroll
    for (int nt = 0; nt < 2; nt++) acc[mt][nt] = (f32x4)0.f;

  for (int k0 = 0; k0 < 512; k0 += 32) {
    if (statsIn) {
#pragma unroll
      for (int it = 0; it < 2; it++) {
        int idx = tid + it * 256;
        int row = idx >> 2, kc = (idx & 3) * 8;
        const float* ap = &Afp[(size_t)(m0 + row) * 512 + k0 + kc];
        float4 va = *(const float4*)ap;
        float4 vb = *(const float4*)(ap + 4);
        float4 ga = *(const float4*)&lng[k0 + kc];
        float4 gb = *(const float4*)&lng[k0 + kc + 4];
        float4 ba = *(const float4*)&lnb[k0 + kc];
        float4 bb = *(const float4*)&lnb[k0 + kc + 4];
        float v[8] = {va.x, va.y, va.z, va.w, vb.x, vb.y, vb.z, vb.w};
        float gg[8] = {ga.x, ga.y, ga.z, ga.w, gb.x, gb.y, gb.z, gb.w};
        float bv[8] = {ba.x, ba.y, ba.z, ba.w, bb.x, bb.y, bb.z, bb.w};
        short8 pk;
#pragma unroll
        for (int k = 0; k < 8; k++) {
          float t = fmaxf((v[k] - mu) * inv * gg[k] + bv[k], 0.f);
          pk[k] = f2bs(t);
        }
        *(short8*)&As[row * 40 + kc] = pk;
      }
    } else {
#pragma unroll
      for (int it = 0; it < 2; it++) {
        int idx = tid + it * 256;
        int row = idx >> 2, kc = (idx & 3) * 8;
        *(short8*)&As[row * 40 + kc] =
            *(const short8*)&Abf[(size_t)(m0 + row) * 512 + k0 + kc];
      }
    }
    {
      int row = tid >> 2, kc = (tid & 3) * 8;
      *(short8*)&Bs[row * 40 + kc] =
          *(const short8*)&B[(size_t)(n0 + row) * 512 + k0 + kc];
    }
    __syncthreads();
    short8 af[4], bfr[2];
#pragma unroll
    for (int mt = 0; mt < 4; mt++)
      af[mt] = *(const short8*)&As[(mh + mt * 16 + l15) * 40 + quad * 8];
#pragma unroll
    for (int nt = 0; nt < 2; nt++)
      bfr[nt] = *(const short8*)&Bs[(nh + nt * 16 + l15) * 40 + quad * 8];
#pragma unroll
    for (int mt = 0; mt < 4; mt++)
#pragma unroll
      for (int nt = 0; nt < 2; nt++)
        acc[mt][nt] = __builtin_amdgcn_mfma_f32_16x16x32_bf16(
            af[mt], bfr[nt], acc[mt][nt], 0, 0, 0);
    __syncthreads();
  }
#pragma unroll
  for (int mt = 0; mt < 4; mt++) {
#pragma unroll
    for (int nt = 0; nt < 2; nt++) {
      int col = n0 + nh + nt * 16 + l15;
      float bv = bias ? bias[col] : 0.f;
#pragma unroll
      for (int r = 0; r < 4; r++) {
        int row = m0 + mh + mt * 16 + quad * 4 + r;
        float v = acc[mt][nt][r] + bv;
        if (C) C[(size_t)row * 512 + col] = v;
        if (Cb) Cb[(size_t)row * 512 + col] = __float2bfloat16(v);
      }
    }
  }
}

// ---------- GAT edge + softmax (fixed self-score offset) + aggregate + LN stats ----
// One wave per dst node; lane owns 8 contiguous dims (16-B gathers, float4 stores).
// 8-edge unroll for MLP; ssrc scalarized; rows kept as short8 (4 VGPR each).
__global__ __launch_bounds__(256) void k_gat_edge(const bf16* __restrict__ xl,
                                                  const bf16* __restrict__ xr,
                                                  const float* __restrict__ att,
                                                  const float* __restrict__ bias,
                                                  const int* __restrict__ offs,
                                                  const int* __restrict__ ssrc,
                                                  float* __restrict__ out,
                                                  float* __restrict__ statsOut) {
  __shared__ float redS[4], redSS[4];
  int wave = (blockIdx.x * blockDim.x + threadIdx.x) >> 6;
  int lane = threadIdx.x & 63;
  int wid = threadIdx.x >> 6;
  if (wave < NN) {
    int n = wave;
    int base = lane * 8;
    float xrv[8], attv[8], acc[8];
    short8 xr8 = *(const short8*)&xr[(size_t)n * 512 + base];
#pragma unroll
    for (int k = 0; k < 8; k++) {
      xrv[k] = s2f(xr8[k]);
      attv[k] = att[base + k];
    }
    // self edge: offset m0 = score(n,n); p_self = 1
    float m0, lsum;
    {
      short8 a8 = *(const short8*)&xl[(size_t)n * 512 + base];
      float sc0 = 0.f;
#pragma unroll
      for (int k = 0; k < 8; k++) {
        float v = s2f(a8[k]);
        acc[k] = v;
        float t = v + xrv[k];
        t = (t > 0.f) ? t : 0.2f * t;
        sc0 += attv[k] * t;
      }
#pragma unroll
      for (int off = 32; off >= 1; off >>= 1) sc0 += __shfl_xor(sc0, off, 64);
      m0 = sc0;
      lsum = 1.f;
    }
    int e0 = offs[n], e1 = offs[n + 1];
    int e = e0;
    for (; e + 7 < e1; e += 8) {
      int sidx[8];
#pragma unroll
      for (int j = 0; j < 8; j++)
        sidx[j] = __builtin_amdgcn_readfirstlane(ssrc[e + j]);
      short8 a[8];
#pragma unroll
      for (int j = 0; j < 8; j++)
        a[j] = *(const short8*)&xl[(size_t)sidx[j] * 512 + base];
      float c[8];
#pragma unroll
      for (int j = 0; j < 8; j++) {
        float sc = 0.f;
#pragma unroll
        for (int k = 0; k < 8; k++) {
          float t = s2f(a[j][k]) + xrv[k];
          t = (t > 0.f) ? t : 0.2f * t;
          sc += attv[k] * t;
        }
        c[j] = sc;
      }
#pragma unroll
      for (int off = 32; off >= 1; off >>= 1)
#pragma unroll
        for (int j = 0; j < 8; j++) c[j] += __shfl_xor(c[j], off, 64);
      float p[8];
#pragma unroll
      for (int j = 0; j < 8; j++) {
        p[j] = __expf(c[j] - m0);
        lsum += p[j];
      }
#pragma unroll
      for (int j = 0; j < 8; j++)
#pragma unroll
        for (int k = 0; k < 8; k++) acc[k] += p[j] * s2f(a[j][k]);
    }
    for (; e + 3 < e1; e += 4) {
      int sidx[4];
#pragma unroll
      for (int j = 0; j < 4; j++)
        sidx[j] = __builtin_amdgcn_readfirstlane(ssrc[e + j]);
      short8 a[4];
#pragma unroll
      for (int j = 0; j < 4; j++)
        a[j] = *(const short8*)&xl[(size_t)sidx[j] * 512 + base];
      float c[4];
#pragma unroll
      for (int j = 0; j < 4; j++) {
        float sc = 0.f;
#pragma unroll
        for (int k = 0; k < 8; k++) {
          float t = s2f(a[j][k]) + xrv[k];
          t = (t > 0.f) ? t : 0.2f * t;
          sc += attv[k] * t;
        }
        c[j] = sc;
      }
#pragma unroll
      for (int off = 32; off >= 1; off >>= 1)
#pragma unroll
        for (int j = 0; j < 4; j++) c[j] += __shfl_xor(c[j], off, 64);
#pragma unroll
      for (int j = 0; j < 4; j++) {
        float p = __expf(c[j] - m0);
        lsum += p;
#pragma unroll
        for (int k = 0; k < 8; k++) acc[k] += p * s2f(a[j][k]);
      }
    }
    for (; e < e1; ++e) {
      int s0 = __builtin_amdgcn_readfirstlane(ssrc[e]);
      short8 a8 = *(const short8*)&xl[(size_t)s0 * 512 + base];
      float sc0 = 0.f;
#pragma unroll
      for (int k = 0; k < 8; k++) {
        float t = s2f(a8[k]) + xrv[k];
        t = (t > 0.f) ? t : 0.2f * t;
        sc0 += attv[k] * t;
      }
#pragma unroll
      for (int off = 32; off >= 1; off >>= 1) sc0 += __shfl_xor(sc0, off, 64);
      float p0 = __expf(sc0 - m0);
      lsum += p0;
#pragma unroll
      for (int k = 0; k < 8; k++) acc[k] += p0 * s2f(a8[k]);
    }
    float inv = 1.f / lsum;
    float o[8];
    float s = 0.f, ss = 0.f;
#pragma unroll
    for (int k = 0; k < 8; k++) {
      o[k] = acc[k] * inv + bias[base + k];
      s += o[k];
      ss += o[k] * o[k];
    }
    float4 st0, st1;
    st0.x = o[0]; st0.y = o[1]; st0.z = o[2]; st0.w = o[3];
    st1.x = o[4]; st1.y = o[5]; st1.z = o[6]; st1.w = o[7];
    *(float4*)&out[(size_t)n * 512 + base] = st0;
    *(float4*)&out[(size_t)n * 512 + base + 4] = st1;
    if (statsOut) {
#pragma unroll
      for (int off = 32; off >= 1; off >>= 1) {
        s += __shfl_xor(s, off, 64);
        ss += __shfl_xor(ss, off, 64);
      }
      if (lane == 0) { redS[wid] = s; redSS[wid] = ss; }
    }
  }
  if (statsOut) {
    __syncthreads();
    if (threadIdx.x == 0) {
      float a = redS[0] + redS[1] + redS[2] + redS[3];
      float b = redSS[0] + redSS[1] + redSS[2] + redSS[3];
      int slot = blockIdx.x & 15;
      atomicAdd(&statsOut[slot], a);
      atomicAdd(&statsOut[16 + slot], b);
    }
  }
}

// ---------- CloudGraph: balanced — wave handles node pair (p, 95-p), 97 edges ----
__global__ __launch_bounds__(256) void k_cloud(const bf16* __restrict__ g1,
                                               const float* __restrict__ ep,
                                               const float* __restrict__ lin1b,
                                               const float* __restrict__ w3,
                                               float* __restrict__ p1,
                                               float* __restrict__ p2) {
  int w = (blockIdx.x * blockDim.x + threadIdx.x) >> 6;
  int lane = threadIdx.x & 63;
  if (w >= NN) return;
  int hf = w & 1;
  int pi = w >> 1;              // [0, 2304)
  int g = pi / 48, pp = pi % 48;
  int d0 = hf * 256 + lane * 4;
  float4 bb = *(const float4*)&lin1b[d0];
  float4 w30 = *(const float4*)&w3[d0];
  float4 w31 = *(const float4*)&w3[512 + d0];
  float4 w32 = *(const float4*)&w3[1024 + d0];
  float bbv[4] = {bb.x, bb.y, bb.z, bb.w};
  float w0v[4] = {w30.x, w30.y, w30.z, w30.w};
  float w1v[4] = {w31.x, w31.y, w31.z, w31.w};
  float w2v[4] = {w32.x, w32.y, w32.z, w32.w};

#pragma unroll
  for (int half = 0; half < 2; half++) {
    int p = half ? (NPG - 1 - pp) : pp;
    int n = g * NPG + p;
    int cnt = NPG - p;
    int slot0 = g * TRIU + p * NPG - (p * (p - 1)) / 2;
    float gi[4], a1[4], a2[4];
    short4v gi4 = *(const short4v*)&g1[(size_t)n * 512 + d0];
#pragma unroll
    for (int k = 0; k < 4; k++) {
      gi[k] = s2f(gi4[k]);
      a1[k] = 0.f;
      a2[k] = 0.f;
    }
    int e = 0;
    for (; e + 1 < cnt; e += 2) {
      float4 pa = *(const float4*)&ep[(size_t)(slot0 + e) * 4];
      float4 pb = *(const float4*)&ep[(size_t)(slot0 + e + 1) * 4];
      short4v ga = *(const short4v*)&g1[(size_t)(n + e) * 512 + d0];
      short4v gb = *(const short4v*)&g1[(size_t)(n + e + 1) * 512 + d0];
#pragma unroll
      for (int k = 0; k < 4; k++) {
        float t = fmaf(pa.w, gi[k] - s2f(ga[k]), bbv[k]);
        a1[k] += fmaxf(t, 0.f);
        float u = fmaf(pb.w, gi[k] - s2f(gb[k]), bbv[k]);
        a1[k] += fmaxf(u, 0.f);
        float t2 = pa.x * w0v[k] + pa.y * w1v[k] + pa.z * w2v[k];
        a2[k] += fmaxf(t2, 0.f);
        float u2 = pb.x * w0v[k] + pb.y * w1v[k] + pb.z * w2v[k];
        a2[k] += fmaxf(u2, 0.f);
      }
    }
    if (e < cnt) {
      float4 pa = *(const float4*)&ep[(size_t)(slot0 + e) * 4];
      short4v ga = *(const short4v*)&g1[(size_t)(n + e) * 512 + d0];
#pragma unroll
      for (int k = 0; k < 4; k++) {
        float t = fmaf(pa.w, gi[k] - s2f(ga[k]), bbv[k]);
        a1[k] += fmaxf(t, 0.f);
        float t2 = pa.x * w0v[k] + pa.y * w1v[k] + pa.z * w2v[k];
        a2[k] += fmaxf(t2, 0.f);
      }
    }
    float4 o1, o2;
    o1.x = a1[0]; o1.y = a1[1]; o1.z = a1[2]; o1.w = a1[3];
    o2.x = a2[0]; o2.y = a2[1]; o2.z = a2[2]; o2.w = a2[3];
    *(float4*)&p1[(size_t)n * 512 + d0] = o1;
    *(float4*)&p2[(size_t)n * 512 + d0] = o2;
  }
}

// ---------- fused cloud epilogue: ln_row(p1) + bn(p2) + fuse -> s_bf ----------
__global__ __launch_bounds__(256) void k_cloud_epi(
    const float* __restrict__ p1, const float* __restrict__ p2,
    const float* __restrict__ h, const float* __restrict__ xg,
    const float* __restrict__ colsum, const float* __restrict__ colsq,
    const float* __restrict__ lng, const float* __restrict__ lnb,
    const float* __restrict__ bng, const float* __restrict__ bnb,
    bf16* __restrict__ s_bf) {
  int wave = (blockIdx.x * blockDim.x + threadIdx.x) >> 6;
  int lane = threadIdx.x & 63;
  if (wave >= NN) return;
  int n = wave;
  size_t rb = (size_t)n * 512 + lane * 8;
  int base = lane * 8;
  float v[8];
  float s = 0.f;
#pragma unroll
  for (int k = 0; k < 8; k++) {
    v[k] = p1[rb + k];
    s += v[k];
  }
#pragma unroll
  for (int off = 32; off >= 1; off >>= 1) s += __shfl_xor(s, off, 64);
  float mu = s * (1.f / 512.f);
  float ss = 0.f;
#pragma unroll
  for (int k = 0; k < 8; k++) {
    float t = v[k] - mu;
    ss += t * t;
  }
#pragma unroll
  for (int off = 32; off >= 1; off >>= 1) ss += __shfl_xor(ss, off, 64);
  float inv = 1.f / sqrtf(ss * (1.f / 512.f) + 1e-5f);
#pragma unroll
  for (int k = 0; k < 8; k++) {
    int d = base + k;
    float ln1 = (v[k] - mu) * inv * lng[d] + lnb[d];
    float cmu = colsum[d] * (1.f / NN);
    float cvar = colsq[d] * (1.f / NN) - cmu * cmu;
    float cinv = 1.f / sqrtf(fmaxf(cvar, 0.f) + 1e-5f);
    float bnv = (p2[rb + k] - cmu) * cinv * bng[d] + bnb[d];
    float out = 2.f * h[rb + k] + xg[rb + k] + ln1 + bnv;
    s_bf[rb + k] = __float2bfloat16(out);
  }
}

// ---------- column (batchnorm) stats ----------
__global__ void k_col_reduce(const float* __restrict__ x, float* colsum, float* colsq) {
  int r0 = blockIdx.x * 128;
  int c0 = threadIdx.x;
  float s0 = 0.f, q0 = 0.f, s1 = 0.f, q1 = 0.f;
  for (int r = r0; r < r0 + 128; ++r) {
    float v = x[(size_t)r * 512 + c0];
    s0 += v;
    q0 += v * v;
    float w = x[(size_t)r * 512 + c0 + 256];
    s1 += w;
    q1 += w * w;
  }
  atomicAdd(&colsum[c0], s0);
  atomicAdd(&colsq[c0], q0);
  atomicAdd(&colsum[c0 + 256], s1);
  atomicAdd(&colsq[c0 + 256], q1);
}
__global__ void k_bn_out(const float* __restrict__ y, const float* __restrict__ colsum,
                         const float* __restrict__ colsq, const float* __restrict__ g,
                         const float* __restrict__ b, float* __restrict__ out) {
  int i = blockIdx.x * blockDim.x + threadIdx.x;
  if (i >= NN * DD) return;
  int d = i & 511;
  float mu = colsum[d] * (1.f / NN);
  float var = colsq[d] * (1.f / NN) - mu * mu;
  float inv = 1.f / sqrtf(fmaxf(var, 0.f) + 1e-5f);
  out[i] = (y[i] - mu) * inv * g[d] + b[d];
}

extern "C" void kernel_launch(void* const* d_in, const int* in_sizes, int n_in,
                              void* d_out, int out_size, void* d_ws, size_t ws_size,
                              hipStream_t stream) {
  const float* x = (const float*)d_in[0];
  const int* ei = (const int*)d_in[1];
  const float* xyz = (const float*)d_in[3];
  const float* x_proj_w = (const float*)d_in[5];
  const float* x_proj_b = (const float*)d_in[6];
  const float* gat_wl = (const float*)d_in[7];
  const float* gat_bl = (const float*)d_in[8];
  const float* gat_wr = (const float*)d_in[9];
  const float* gat_br = (const float*)d_in[10];
  const float* gat_att = (const float*)d_in[11];
  const float* gat_bias = (const float*)d_in[12];
  const float* gat_ln_g = (const float*)d_in[13];
  const float* gat_ln_b = (const float*)d_in[14];
  const float* cg_xyz_w = (const float*)d_in[15];
  const float* cg_bn_g = (const float*)d_in[16];
  const float* cg_bn_b = (const float*)d_in[17];
  const float* cg_lin1_w = (const float*)d_in[18];
  const float* cg_lin1_b = (const float*)d_in[19];
  const float* cg_ln_g = (const float*)d_in[20];
  const float* cg_ln_b = (const float*)d_in[21];
  const float* lin_w = (const float*)d_in[22];
  const float* lin_b = (const float*)d_in[23];
  const float* bn_g = (const float*)d_in[24];
  const float* bn_b = (const float*)d_in[25];

  const size_t ND = (size_t)NN * DD;
  char* w = (char*)d_ws;
  float* h = (float*)w;        w += ND * 4;
  float* xg = (float*)w;       w += ND * 4;
  float* p1 = (float*)w;       w += ND * 4;  // alias: final y
  float* p2 = (float*)w;       w += ND * 4;
  bf16* h_bf = (bf16*)w;       w += ND * 2;  // alias: s_bf (after cloud GEMM)
  bf16* xl_bf = (bf16*)w;      w += ND * 2;  // alias: g1_bf (after GAT)
  bf16* xr_bf = (bf16*)w;      w += ND * 2;
  bf16* Wt = (bf16*)w;         w += (size_t)14 * NK * 2;
  float* eparam = (float*)w;   w += (size_t)BG * TRIU * 16;
  int* counts = (int*)w;       w += NN * 4;
  int* offs = (int*)w;         w += (NN + 4) * 4;
  int* cursor = (int*)w;       w += NN * 4;
  int* ssrc = (int*)w;         w += EREAL * 4;
  float* statsAll = (float*)w; w += 5 * 32 * 4;
  float* colsum = (float*)w;   w += 512 * 4;
  float* colsq = (float*)w;    w += 512 * 4;
  float* y = p1;
  bf16* g1_bf = xl_bf;
  bf16* s_bf = h_bf;

  const int TPB = 256;
  const int ND_BLK = (int)((ND + TPB - 1) / TPB);

  k_wt<<<dim3(16, 16, 14), TPB, 0, stream>>>(gat_wl, gat_wr, cg_lin1_w, lin_w, Wt,
                                             counts, statsAll);
  k_xproj<<<ND_BLK, TPB, 0, stream>>>(x, x_proj_w, x_proj_b, ei, xyz, h, h_bf,
                                      counts, eparam);
  k_scan<<<1, 256, 0, stream>>>(counts, offs, cursor);
  k_scatter<<<(EREAL + TPB - 1) / TPB, TPB, 0, stream>>>(ei, cursor, ssrc);

  for (int l = 0; l < NLAYER; l++) {
    const float* sIn = (l > 0) ? statsAll + 32 * (l - 1) : nullptr;
    const float* lg = (l > 0) ? gat_ln_g + (l - 1) * DD : nullptr;
    const float* lb = (l > 0) ? gat_ln_b + (l - 1) * DD : nullptr;
    k_gemm<<<dim3(36, 8, 2), TPB, 0, stream>>>(
        xg, h_bf, Wt + (size_t)l * NK, Wt + (size_t)(6 + l) * NK,
        gat_bl + l * DD, gat_br + l * DD, nullptr, nullptr, xl_bf, xr_bf,
        sIn, lg, lb, nullptr, 0);
    float* sOut = (l < NLAYER - 1) ? statsAll + 32 * l : nullptr;
    k_gat_edge<<<NN / 4, TPB, 0, stream>>>(xl_bf, xr_bf, gat_att + l * DD,
                                           gat_bias + l * DD, offs, ssrc, xg, sOut);
  }

  // CloudGraph: g1 = h @ cg_lin1_w (no bias), bf16 out; zero colsum for p2 BN
  k_gemm<<<dim3(36, 8, 1), TPB, 0, stream>>>(
      nullptr, h_bf, Wt + (size_t)12 * NK, Wt + (size_t)12 * NK, nullptr, nullptr,
      nullptr, nullptr, g1_bf, g1_bf, nullptr, nullptr, nullptr, colsum, 1024);
  k_cloud<<<NN / 4, TPB, 0, stream>>>(g1_bf, eparam, cg_lin1_b, cg_xyz_w, p1, p2);
  k_col_reduce<<<36, 256, 0, stream>>>(p2, colsum, colsq);
  k_cloud_epi<<<NN / 4, TPB, 0, stream>>>(p1, p2, h, xg, colsum, colsq,
                                          cg_ln_g, cg_ln_b, cg_bn_g, cg_bn_b, s_bf);

  // final: y = s @ lin_w + lin_b (fp32), zero colsum for output BN
  k_gemm<<<dim3(36, 8, 1), TPB, 0, stream>>>(
      nullptr, s_bf, Wt + (size_t)13 * NK, Wt + (size_t)13 * NK, lin_b, lin_b,
      y, y, nullptr, nullptr, nullptr, nullptr, nullptr, colsum, 1024);
  k_col_reduce<<<36, 256, 0, stream>>>(y, colsum, colsq);
  k_bn_out<<<ND_BLK, TPB, 0, stream>>>(y, colsum, colsq, bn_g, bn_b, (float*)d_out);
}

// Round 10
// 645.142 us; speedup vs baseline: 1.0505x; 1.0505x over previous
//
#include <hip/hip_runtime.h>
#include <hip/hip_bf16.h>

#define NN 4608
#define BG 48
#define NPG 96
#define DD 512
#define XDIM 16
#define EREAL 147456
#define NLAYER 6
#define NK 262144     // 512*512
#define TRIU 4656     // 96*97/2

typedef __hip_bfloat16 bf16;
typedef short short8 __attribute__((ext_vector_type(8)));
typedef short short4v __attribute__((ext_vector_type(4)));
typedef float f32x4 __attribute__((ext_vector_type(4)));

// bf16 bits (as short) -> float: shift left 16
__device__ __forceinline__ float s2f(short s) {
  return __uint_as_float(((unsigned int)(unsigned short)s) << 16);
}
__device__ __forceinline__ short f2bs(float f) {
  bf16 h = __float2bfloat16(f);
  short s;
  __builtin_memcpy(&s, &h, 2);
  return s;
}

// ---------- weight transpose + bf16 convert; also zero counts & statsAll ----------
__global__ __launch_bounds__(256) void k_wt(const float* __restrict__ wl,
                                            const float* __restrict__ wr,
                                            const float* __restrict__ cg,
                                            const float* __restrict__ lin,
                                            bf16* __restrict__ Wt,
                                            int* __restrict__ counts,
                                            float* __restrict__ statsAll) {
  if (blockIdx.z == 0) {
    int id = (blockIdx.y * 16 + blockIdx.x) * 256 + threadIdx.x;
    if (id < NN) counts[id] = 0;
    if (id < 5 * 32) statsAll[id] = 0.f;
  }
  __shared__ float tile[32][33];
  int z = blockIdx.z;
  const float* src = (z < 6) ? wl + (size_t)z * NK
                   : (z < 12) ? wr + (size_t)(z - 6) * NK
                   : (z == 12) ? cg : lin;
  bf16* dst = Wt + (size_t)z * NK;
  int c = threadIdx.x & 31;
  int r0 = threadIdx.x >> 5;  // 0..7
  int bx = blockIdx.x * 32, by = blockIdx.y * 32;
#pragma unroll
  for (int i = 0; i < 4; i++) {
    int r = r0 + i * 8;
    tile[r][c] = src[(size_t)(by + r) * 512 + bx + c];  // [k][n]
  }
  __syncthreads();
#pragma unroll
  for (int i = 0; i < 4; i++) {
    int r = r0 + i * 8;  // n within tile
    dst[(size_t)(bx + r) * 512 + by + c] = __float2bfloat16(tile[c][r]);
  }
}

// ---------- x projection + edge histogram + cloud edge params ----------
__global__ void k_xproj(const float* __restrict__ x, const float* __restrict__ w,
                        const float* __restrict__ b, const int* __restrict__ ei,
                        const float* __restrict__ xyz, float* __restrict__ h,
                        bf16* __restrict__ h_bf, int* __restrict__ counts,
                        float* __restrict__ ep) {
  int i = blockIdx.x * blockDim.x + threadIdx.x;
  if (i >= NN * DD) return;
  if (i < EREAL) atomicAdd(&counts[ei[EREAL + i]], 1);
  if (i < NN * NPG) {
    int n = i / NPG, e = i - n * NPG;
    int p = n % NPG;
    if (e < NPG - p) {
      int g = n / NPG;
      int slot = g * TRIU + p * NPG - (p * (p - 1)) / 2 + e;
      int j = n + e;
      float dx = xyz[n * 3] - xyz[j * 3];
      float dy = xyz[n * 3 + 1] - xyz[j * 3 + 1];
      float dz = xyz[n * 3 + 2] - xyz[j * 3 + 2];
      float sq = dx * dx + dy * dy + dz * dz;
      float dist = (sq > 0.f) ? sqrtf(sq) : 0.f;
      float4 v;
      v.x = dx; v.y = dy; v.z = dz; v.w = __expf(-dist);
      *(float4*)&ep[(size_t)slot * 4] = v;
    }
  }
  int n = i >> 9, d = i & 511;
  float acc = b[d];
#pragma unroll
  for (int k = 0; k < XDIM; k++) acc += x[n * XDIM + k] * w[k * DD + d];
  h[i] = acc;
  h_bf[i] = __float2bfloat16(acc);
}

// ---------- edge sort (counting sort by dst; self loops handled in gat_edge) ----------
__global__ void k_scan(const int* __restrict__ counts, int* offsets, int* cursor) {
  __shared__ int part[256];
  __shared__ int pre[256];
  int t = threadIdx.x;
  int base = t * 18;  // 4608/256
  int s = 0;
#pragma unroll
  for (int i = 0; i < 18; i++) s += counts[base + i];
  part[t] = s;
  __syncthreads();
  if (t == 0) {
    int r = 0;
    for (int i = 0; i < 256; i++) { pre[i] = r; r += part[i]; }
  }
  __syncthreads();
  int run = pre[t];
#pragma unroll
  for (int i = 0; i < 18; i++) {
    offsets[base + i] = run;
    cursor[base + i] = run;
    run += counts[base + i];
  }
  if (t == 0) offsets[NN] = EREAL;
}
__global__ void k_scatter(const int* __restrict__ ei, int* cursor, int* ssrc) {
  int e = blockIdx.x * blockDim.x + threadIdx.x;
  if (e < EREAL) {
    int s = ei[e], d = ei[EREAL + e];
    int pos = atomicAdd(&cursor[d], 1);
    ssrc[pos] = s;
  }
}

// ---------- MFMA GEMM: C[4608,512] = A[4608,512] @ Wt^T + bias ----------
// A either bf16 (Abf) or fp32 (Afp) with fused graph-LN+relu (statsIn != null).
// BM=128 BN=64 BK=32, 4 waves. blockIdx.z picks slot 0/1 (B/bias/out).
__global__ __launch_bounds__(256) void k_gemm(
    const float* __restrict__ Afp, const bf16* __restrict__ Abf,
    const bf16* __restrict__ B0, const bf16* __restrict__ B1,
    const float* __restrict__ bias0, const float* __restrict__ bias1,
    float* __restrict__ C0, float* __restrict__ C1,
    bf16* __restrict__ Cb0, bf16* __restrict__ Cb1,
    const float* __restrict__ statsIn,
    const float* __restrict__ lng, const float* __restrict__ lnb,
    float* __restrict__ zptr, int zn) {
  if (zptr && blockIdx.x == 0 && blockIdx.y == 0 && blockIdx.z == 0) {
    for (int i = threadIdx.x; i < zn; i += 256) zptr[i] = 0.f;
  }
  __shared__ __align__(16) bf16 As[128 * 40];
  __shared__ __align__(16) bf16 Bs[64 * 40];
  const bf16* B = blockIdx.z ? B1 : B0;
  const float* bias = blockIdx.z ? bias1 : bias0;
  float* C = blockIdx.z ? C1 : C0;
  bf16* Cb = blockIdx.z ? Cb1 : Cb0;
  int tid = threadIdx.x;
  int m0 = blockIdx.x * 128, n0 = blockIdx.y * 64;
  int lane = tid & 63, wid = tid >> 6;
  int mh = (wid >> 1) * 64, nh = (wid & 1) * 32;
  int l15 = lane & 15, quad = lane >> 4;

  float mu = 0.f, inv = 1.f;
  if (statsIn) {
    float s = 0.f, ss = 0.f;
#pragma unroll
    for (int i = 0; i < 16; i++) { s += statsIn[i]; ss += statsIn[16 + i]; }
    const float invM = 1.f / ((float)NN * (float)DD);
    mu = s * invM;
    float var = ss * invM - mu * mu;
    float sd = sqrtf(fmaxf(var, 0.f));
    inv = 1.f / (sd + 1e-5f);
  }

  f32x4 acc[4][2];
#pragma unroll
  for (int mt = 0; mt < 4; mt++)
#pragma unroll
    for (int nt = 0; nt < 2; nt++) acc[mt][nt] = (f32x4)0.f;

  for (int k0 = 0; k0 < 512; k0 += 32) {
    if (statsIn) {
#pragma unroll
      for (int it = 0; it < 2; it++) {
        int idx = tid + it * 256;
        int row = idx >> 2, kc = (idx & 3) * 8;
        const float* ap = &Afp[(size_t)(m0 + row) * 512 + k0 + kc];
        float4 va = *(const float4*)ap;
        float4 vb = *(const float4*)(ap + 4);
        float4 ga = *(const float4*)&lng[k0 + kc];
        float4 gb = *(const float4*)&lng[k0 + kc + 4];
        float4 ba = *(const float4*)&lnb[k0 + kc];
        float4 bb = *(const float4*)&lnb[k0 + kc + 4];
        float v[8] = {va.x, va.y, va.z, va.w, vb.x, vb.y, vb.z, vb.w};
        float gg[8] = {ga.x, ga.y, ga.z, ga.w, gb.x, gb.y, gb.z, gb.w};
        float bv[8] = {ba.x, ba.y, ba.z, ba.w, bb.x, bb.y, bb.z, bb.w};
        short8 pk;
#pragma unroll
        for (int k = 0; k < 8; k++) {
          float t = fmaxf((v[k] - mu) * inv * gg[k] + bv[k], 0.f);
          pk[k] = f2bs(t);
        }
        *(short8*)&As[row * 40 + kc] = pk;
      }
    } else {
#pragma unroll
      for (int it = 0; it < 2; it++) {
        int idx = tid + it * 256;
        int row = idx >> 2, kc = (idx & 3) * 8;
        *(short8*)&As[row * 40 + kc] =
            *(const short8*)&Abf[(size_t)(m0 + row) * 512 + k0 + kc];
      }
    }
    {
      int row = tid >> 2, kc = (tid & 3) * 8;
      *(short8*)&Bs[row * 40 + kc] =
          *(const short8*)&B[(size_t)(n0 + row) * 512 + k0 + kc];
    }
    __syncthreads();
    short8 af[4], bfr[2];
#pragma unroll
    for (int mt = 0; mt < 4; mt++)
      af[mt] = *(const short8*)&As[(mh + mt * 16 + l15) * 40 + quad * 8];
#pragma unroll
    for (int nt = 0; nt < 2; nt++)
      bfr[nt] = *(const short8*)&Bs[(nh + nt * 16 + l15) * 40 + quad * 8];
#pragma unroll
    for (int mt = 0; mt < 4; mt++)
#pragma unroll
      for (int nt = 0; nt < 2; nt++)
        acc[mt][nt] = __builtin_amdgcn_mfma_f32_16x16x32_bf16(
            af[mt], bfr[nt], acc[mt][nt], 0, 0, 0);
    __syncthreads();
  }
#pragma unroll
  for (int mt = 0; mt < 4; mt++) {
#pragma unroll
    for (int nt = 0; nt < 2; nt++) {
      int col = n0 + nh + nt * 16 + l15;
      float bv = bias ? bias[col] : 0.f;
#pragma unroll
      for (int r = 0; r < 4; r++) {
        int row = m0 + mh + mt * 16 + quad * 4 + r;
        float v = acc[mt][nt][r] + bv;
        if (C) C[(size_t)row * 512 + col] = v;
        if (Cb) Cb[(size_t)row * 512 + col] = __float2bfloat16(v);
      }
    }
  }
}

// ---------- GAT edge: TWO waves per dst node (edge-list split), fixed-offset
// softmax, 4-edge unroll, LDS combine. Lane owns 8 contiguous dims. ----------
__global__ __launch_bounds__(256) void k_gat_edge(const bf16* __restrict__ xl,
                                                  const bf16* __restrict__ xr,
                                                  const float* __restrict__ att,
                                                  const float* __restrict__ bias,
                                                  const int* __restrict__ offs,
                                                  const int* __restrict__ ssrc,
                                                  float* __restrict__ out,
                                                  float* __restrict__ statsOut) {
  __shared__ float accS[2][64 * 9];  // +1 pad per 8 to break bank stride
  __shared__ float lsumS[2];
  __shared__ float redS[2], redSS[2];
  int widx = threadIdx.x >> 6;   // 0..3
  int slot = widx >> 1;          // node slot in block: 0..1
  int hf = widx & 1;             // which half of the edge list
  int lane = threadIdx.x & 63;
  int n = blockIdx.x * 2 + slot; // grid = NN/2, always valid
  int base = lane * 8;
  float xrv[8], attv[8], acc[8];
  short8 xr8 = *(const short8*)&xr[(size_t)n * 512 + base];
#pragma unroll
  for (int k = 0; k < 8; k++) {
    xrv[k] = s2f(xr8[k]);
    attv[k] = att[base + k];
  }
  // self edge: offset m0 = score(n,n); only hf==0 wave takes its contribution
  float m0, lsum;
  {
    short8 a8 = *(const short8*)&xl[(size_t)n * 512 + base];
    float sc0 = 0.f;
    float xs[8];
#pragma unroll
    for (int k = 0; k < 8; k++) {
      float v = s2f(a8[k]);
      xs[k] = v;
      float t = v + xrv[k];
      t = (t > 0.f) ? t : 0.2f * t;
      sc0 += attv[k] * t;
    }
#pragma unroll
    for (int off = 32; off >= 1; off >>= 1) sc0 += __shfl_xor(sc0, off, 64);
    m0 = sc0;
    if (hf == 0) {
      lsum = 1.f;
#pragma unroll
      for (int k = 0; k < 8; k++) acc[k] = xs[k];
    } else {
      lsum = 0.f;
#pragma unroll
      for (int k = 0; k < 8; k++) acc[k] = 0.f;
    }
  }
  int e0 = offs[n], e1 = offs[n + 1];
  int cnt = e1 - e0;
  int half0 = (cnt + 1) >> 1;
  int e = hf ? e0 + half0 : e0;
  int ee = hf ? e1 : e0 + half0;
  for (; e + 3 < ee; e += 4) {
    int s0 = ssrc[e], s1 = ssrc[e + 1], s2 = ssrc[e + 2], s3 = ssrc[e + 3];
    short8 a0 = *(const short8*)&xl[(size_t)s0 * 512 + base];
    short8 a1 = *(const short8*)&xl[(size_t)s1 * 512 + base];
    short8 a2 = *(const short8*)&xl[(size_t)s2 * 512 + base];
    short8 a3 = *(const short8*)&xl[(size_t)s3 * 512 + base];
    float x0[8], x1[8], x2[8], x3[8];
    float c0 = 0.f, c1 = 0.f, c2 = 0.f, c3 = 0.f;
#pragma unroll
    for (int k = 0; k < 8; k++) {
      float v0 = s2f(a0[k]), v1 = s2f(a1[k]), v2 = s2f(a2[k]), v3 = s2f(a3[k]);
      x0[k] = v0; x1[k] = v1; x2[k] = v2; x3[k] = v3;
      float t0 = v0 + xrv[k]; t0 = (t0 > 0.f) ? t0 : 0.2f * t0; c0 += attv[k] * t0;
      float t1 = v1 + xrv[k]; t1 = (t1 > 0.f) ? t1 : 0.2f * t1; c1 += attv[k] * t1;
      float t2 = v2 + xrv[k]; t2 = (t2 > 0.f) ? t2 : 0.2f * t2; c2 += attv[k] * t2;
      float t3 = v3 + xrv[k]; t3 = (t3 > 0.f) ? t3 : 0.2f * t3; c3 += attv[k] * t3;
    }
#pragma unroll
    for (int off = 32; off >= 1; off >>= 1) {
      c0 += __shfl_xor(c0, off, 64);
      c1 += __shfl_xor(c1, off, 64);
      c2 += __shfl_xor(c2, off, 64);
      c3 += __shfl_xor(c3, off, 64);
    }
    float p0 = __expf(c0 - m0), p1 = __expf(c1 - m0);
    float p2 = __expf(c2 - m0), p3 = __expf(c3 - m0);
    lsum += p0 + p1 + p2 + p3;
#pragma unroll
    for (int k = 0; k < 8; k++)
      acc[k] += p0 * x0[k] + p1 * x1[k] + p2 * x2[k] + p3 * x3[k];
  }
  for (; e < ee; ++e) {
    int s0 = ssrc[e];
    short8 a8 = *(const short8*)&xl[(size_t)s0 * 512 + base];
    float x0[8];
    float sc0 = 0.f;
#pragma unroll
    for (int k = 0; k < 8; k++) {
      float v0 = s2f(a8[k]);
      x0[k] = v0;
      float t0 = v0 + xrv[k];
      t0 = (t0 > 0.f) ? t0 : 0.2f * t0;
      sc0 += attv[k] * t0;
    }
#pragma unroll
    for (int off = 32; off >= 1; off >>= 1) sc0 += __shfl_xor(sc0, off, 64);
    float p0 = __expf(sc0 - m0);
    lsum += p0;
#pragma unroll
    for (int k = 0; k < 8; k++) acc[k] += p0 * x0[k];
  }
  // combine the two halves through LDS
  if (hf == 1) {
#pragma unroll
    for (int k = 0; k < 8; k++) accS[slot][lane * 9 + k] = acc[k];
    if (lane == 0) lsumS[slot] = lsum;
  }
  __syncthreads();
  if (hf == 0) {
#pragma unroll
    for (int k = 0; k < 8; k++) acc[k] += accS[slot][lane * 9 + k];
    lsum += lsumS[slot];
    float inv = 1.f / lsum;
    float o[8];
    float s = 0.f, ss = 0.f;
#pragma unroll
    for (int k = 0; k < 8; k++) {
      o[k] = acc[k] * inv + bias[base + k];
      s += o[k];
      ss += o[k] * o[k];
    }
    float4 st0, st1;
    st0.x = o[0]; st0.y = o[1]; st0.z = o[2]; st0.w = o[3];
    st1.x = o[4]; st1.y = o[5]; st1.z = o[6]; st1.w = o[7];
    *(float4*)&out[(size_t)n * 512 + base] = st0;
    *(float4*)&out[(size_t)n * 512 + base + 4] = st1;
    if (statsOut) {
#pragma unroll
      for (int off = 32; off >= 1; off >>= 1) {
        s += __shfl_xor(s, off, 64);
        ss += __shfl_xor(ss, off, 64);
      }
      if (lane == 0) { redS[slot] = s; redSS[slot] = ss; }
    }
  }
  if (statsOut) {
    __syncthreads();
    if (threadIdx.x == 0) {
      float a = redS[0] + redS[1];
      float b = redSS[0] + redSS[1];
      int slotA = blockIdx.x & 15;
      atomicAdd(&statsOut[slotA], a);
      atomicAdd(&statsOut[16 + slotA], b);
    }
  }
}

// ---------- CloudGraph: balanced — wave handles node pair (p, 95-p), 97 edges ----
__global__ __launch_bounds__(256) void k_cloud(const bf16* __restrict__ g1,
                                               const float* __restrict__ ep,
                                               const float* __restrict__ lin1b,
                                               const float* __restrict__ w3,
                                               float* __restrict__ p1,
                                               float* __restrict__ p2) {
  int w = (blockIdx.x * blockDim.x + threadIdx.x) >> 6;
  int lane = threadIdx.x & 63;
  if (w >= NN) return;
  int hf = w & 1;
  int pi = w >> 1;              // [0, 2304)
  int g = pi / 48, pp = pi % 48;
  int d0 = hf * 256 + lane * 4;
  float4 bb = *(const float4*)&lin1b[d0];
  float4 w30 = *(const float4*)&w3[d0];
  float4 w31 = *(const float4*)&w3[512 + d0];
  float4 w32 = *(const float4*)&w3[1024 + d0];
  float bbv[4] = {bb.x, bb.y, bb.z, bb.w};
  float w0v[4] = {w30.x, w30.y, w30.z, w30.w};
  float w1v[4] = {w31.x, w31.y, w31.z, w31.w};
  float w2v[4] = {w32.x, w32.y, w32.z, w32.w};

#pragma unroll
  for (int half = 0; half < 2; half++) {
    int p = half ? (NPG - 1 - pp) : pp;
    int n = g * NPG + p;
    int cnt = NPG - p;
    int slot0 = g * TRIU + p * NPG - (p * (p - 1)) / 2;
    float gi[4], a1[4], a2[4];
    short4v gi4 = *(const short4v*)&g1[(size_t)n * 512 + d0];
#pragma unroll
    for (int k = 0; k < 4; k++) {
      gi[k] = s2f(gi4[k]);
      a1[k] = 0.f;
      a2[k] = 0.f;
    }
    int e = 0;
    for (; e + 1 < cnt; e += 2) {
      float4 pa = *(const float4*)&ep[(size_t)(slot0 + e) * 4];
      float4 pb = *(const float4*)&ep[(size_t)(slot0 + e + 1) * 4];
      short4v ga = *(const short4v*)&g1[(size_t)(n + e) * 512 + d0];
      short4v gb = *(const short4v*)&g1[(size_t)(n + e + 1) * 512 + d0];
#pragma unroll
      for (int k = 0; k < 4; k++) {
        float t = fmaf(pa.w, gi[k] - s2f(ga[k]), bbv[k]);
        a1[k] += fmaxf(t, 0.f);
        float u = fmaf(pb.w, gi[k] - s2f(gb[k]), bbv[k]);
        a1[k] += fmaxf(u, 0.f);
        float t2 = pa.x * w0v[k] + pa.y * w1v[k] + pa.z * w2v[k];
        a2[k] += fmaxf(t2, 0.f);
        float u2 = pb.x * w0v[k] + pb.y * w1v[k] + pb.z * w2v[k];
        a2[k] += fmaxf(u2, 0.f);
      }
    }
    if (e < cnt) {
      float4 pa = *(const float4*)&ep[(size_t)(slot0 + e) * 4];
      short4v ga = *(const short4v*)&g1[(size_t)(n + e) * 512 + d0];
#pragma unroll
      for (int k = 0; k < 4; k++) {
        float t = fmaf(pa.w, gi[k] - s2f(ga[k]), bbv[k]);
        a1[k] += fmaxf(t, 0.f);
        float t2 = pa.x * w0v[k] + pa.y * w1v[k] + pa.z * w2v[k];
        a2[k] += fmaxf(t2, 0.f);
      }
    }
    float4 o1, o2;
    o1.x = a1[0]; o1.y = a1[1]; o1.z = a1[2]; o1.w = a1[3];
    o2.x = a2[0]; o2.y = a2[1]; o2.z = a2[2]; o2.w = a2[3];
    *(float4*)&p1[(size_t)n * 512 + d0] = o1;
    *(float4*)&p2[(size_t)n * 512 + d0] = o2;
  }
}

// ---------- fused cloud epilogue: ln_row(p1) + bn(p2) + fuse -> s_bf ----------
__global__ __launch_bounds__(256) void k_cloud_epi(
    const float* __restrict__ p1, const float* __restrict__ p2,
    const float* __restrict__ h, const float* __restrict__ xg,
    const float* __restrict__ colsum, const float* __restrict__ colsq,
    const float* __restrict__ lng, const float* __restrict__ lnb,
    const float* __restrict__ bng, const float* __restrict__ bnb,
    bf16* __restrict__ s_bf) {
  int wave = (blockIdx.x * blockDim.x + threadIdx.x) >> 6;
  int lane = threadIdx.x & 63;
  if (wave >= NN) return;
  int n = wave;
  size_t rb = (size_t)n * 512 + lane * 8;
  int base = lane * 8;
  float v[8];
  float s = 0.f;
#pragma unroll
  for (int k = 0; k < 8; k++) {
    v[k] = p1[rb + k];
    s += v[k];
  }
#pragma unroll
  for (int off = 32; off >= 1; off >>= 1) s += __shfl_xor(s, off, 64);
  float mu = s * (1.f / 512.f);
  float ss = 0.f;
#pragma unroll
  for (int k = 0; k < 8; k++) {
    float t = v[k] - mu;
    ss += t * t;
  }
#pragma unroll
  for (int off = 32; off >= 1; off >>= 1) ss += __shfl_xor(ss, off, 64);
  float inv = 1.f / sqrtf(ss * (1.f / 512.f) + 1e-5f);
#pragma unroll
  for (int k = 0; k < 8; k++) {
    int d = base + k;
    float ln1 = (v[k] - mu) * inv * lng[d] + lnb[d];
    float cmu = colsum[d] * (1.f / NN);
    float cvar = colsq[d] * (1.f / NN) - cmu * cmu;
    float cinv = 1.f / sqrtf(fmaxf(cvar, 0.f) + 1e-5f);
    float bnv = (p2[rb + k] - cmu) * cinv * bng[d] + bnb[d];
    float out = 2.f * h[rb + k] + xg[rb + k] + ln1 + bnv;
    s_bf[rb + k] = __float2bfloat16(out);
  }
}

// ---------- column (batchnorm) stats ----------
__global__ void k_col_reduce(const float* __restrict__ x, float* colsum, float* colsq) {
  int r0 = blockIdx.x * 128;
  int c0 = threadIdx.x;
  float s0 = 0.f, q0 = 0.f, s1 = 0.f, q1 = 0.f;
  for (int r = r0; r < r0 + 128; ++r) {
    float v = x[(size_t)r * 512 + c0];
    s0 += v;
    q0 += v * v;
    float w = x[(size_t)r * 512 + c0 + 256];
    s1 += w;
    q1 += w * w;
  }
  atomicAdd(&colsum[c0], s0);
  atomicAdd(&colsq[c0], q0);
  atomicAdd(&colsum[c0 + 256], s1);
  atomicAdd(&colsq[c0 + 256], q1);
}
__global__ void k_bn_out(const float* __restrict__ y, const float* __restrict__ colsum,
                         const float* __restrict__ colsq, const float* __restrict__ g,
                         const float* __restrict__ b, float* __restrict__ out) {
  int i = blockIdx.x * blockDim.x + threadIdx.x;
  if (i >= NN * DD) return;
  int d = i & 511;
  float mu = colsum[d] * (1.f / NN);
  float var = colsq[d] * (1.f / NN) - mu * mu;
  float inv = 1.f / sqrtf(fmaxf(var, 0.f) + 1e-5f);
  out[i] = (y[i] - mu) * inv * g[d] + b[d];
}

extern "C" void kernel_launch(void* const* d_in, const int* in_sizes, int n_in,
                              void* d_out, int out_size, void* d_ws, size_t ws_size,
                              hipStream_t stream) {
  const float* x = (const float*)d_in[0];
  const int* ei = (const int*)d_in[1];
  const float* xyz = (const float*)d_in[3];
  const float* x_proj_w = (const float*)d_in[5];
  const float* x_proj_b = (const float*)d_in[6];
  const float* gat_wl = (const float*)d_in[7];
  const float* gat_bl = (const float*)d_in[8];
  const float* gat_wr = (const float*)d_in[9];
  const float* gat_br = (const float*)d_in[10];
  const float* gat_att = (const float*)d_in[11];
  const float* gat_bias = (const float*)d_in[12];
  const float* gat_ln_g = (const float*)d_in[13];
  const float* gat_ln_b = (const float*)d_in[14];
  const float* cg_xyz_w = (const float*)d_in[15];
  const float* cg_bn_g = (const float*)d_in[16];
  const float* cg_bn_b = (const float*)d_in[17];
  const float* cg_lin1_w = (const float*)d_in[18];
  const float* cg_lin1_b = (const float*)d_in[19];
  const float* cg_ln_g = (const float*)d_in[20];
  const float* cg_ln_b = (const float*)d_in[21];
  const float* lin_w = (const float*)d_in[22];
  const float* lin_b = (const float*)d_in[23];
  const float* bn_g = (const float*)d_in[24];
  const float* bn_b = (const float*)d_in[25];

  const size_t ND = (size_t)NN * DD;
  char* w = (char*)d_ws;
  float* h = (float*)w;        w += ND * 4;
  float* xg = (float*)w;       w += ND * 4;
  float* p1 = (float*)w;       w += ND * 4;  // alias: final y
  float* p2 = (float*)w;       w += ND * 4;
  bf16* h_bf = (bf16*)w;       w += ND * 2;  // alias: s_bf (after cloud GEMM)
  bf16* xl_bf = (bf16*)w;      w += ND * 2;  // alias: g1_bf (after GAT)
  bf16* xr_bf = (bf16*)w;      w += ND * 2;
  bf16* Wt = (bf16*)w;         w += (size_t)14 * NK * 2;
  float* eparam = (float*)w;   w += (size_t)BG * TRIU * 16;
  int* counts = (int*)w;       w += NN * 4;
  int* offs = (int*)w;         w += (NN + 4) * 4;
  int* cursor = (int*)w;       w += NN * 4;
  int* ssrc = (int*)w;         w += EREAL * 4;
  float* statsAll = (float*)w; w += 5 * 32 * 4;
  float* colsum = (float*)w;   w += 512 * 4;
  float* colsq = (float*)w;    w += 512 * 4;
  float* y = p1;
  bf16* g1_bf = xl_bf;
  bf16* s_bf = h_bf;

  const int TPB = 256;
  const int ND_BLK = (int)((ND + TPB - 1) / TPB);

  k_wt<<<dim3(16, 16, 14), TPB, 0, stream>>>(gat_wl, gat_wr, cg_lin1_w, lin_w, Wt,
                                             counts, statsAll);
  k_xproj<<<ND_BLK, TPB, 0, stream>>>(x, x_proj_w, x_proj_b, ei, xyz, h, h_bf,
                                      counts, eparam);
  k_scan<<<1, 256, 0, stream>>>(counts, offs, cursor);
  k_scatter<<<(EREAL + TPB - 1) / TPB, TPB, 0, stream>>>(ei, cursor, ssrc);

  for (int l = 0; l < NLAYER; l++) {
    const float* sIn = (l > 0) ? statsAll + 32 * (l - 1) : nullptr;
    const float* lg = (l > 0) ? gat_ln_g + (l - 1) * DD : nullptr;
    const float* lb = (l > 0) ? gat_ln_b + (l - 1) * DD : nullptr;
    k_gemm<<<dim3(36, 8, 2), TPB, 0, stream>>>(
        xg, h_bf, Wt + (size_t)l * NK, Wt + (size_t)(6 + l) * NK,
        gat_bl + l * DD, gat_br + l * DD, nullptr, nullptr, xl_bf, xr_bf,
        sIn, lg, lb, nullptr, 0);
    float* sOut = (l < NLAYER - 1) ? statsAll + 32 * l : nullptr;
    k_gat_edge<<<NN / 2, TPB, 0, stream>>>(xl_bf, xr_bf, gat_att + l * DD,
                                           gat_bias + l * DD, offs, ssrc, xg, sOut);
  }

  // CloudGraph: g1 = h @ cg_lin1_w (no bias), bf16 out; zero colsum for p2 BN
  k_gemm<<<dim3(36, 8, 1), TPB, 0, stream>>>(
      nullptr, h_bf, Wt + (size_t)12 * NK, Wt + (size_t)12 * NK, nullptr, nullptr,
      nullptr, nullptr, g1_bf, g1_bf, nullptr, nullptr, nullptr, colsum, 1024);
  k_cloud<<<NN / 4, TPB, 0, stream>>>(g1_bf, eparam, cg_lin1_b, cg_xyz_w, p1, p2);
  k_col_reduce<<<36, 256, 0, stream>>>(p2, colsum, colsq);
  k_cloud_epi<<<NN / 4, TPB, 0, stream>>>(p1, p2, h, xg, colsum, colsq,
                                          cg_ln_g, cg_ln_b, cg_bn_g, cg_bn_b, s_bf);

  // final: y = s @ lin_w + lin_b (fp32), zero colsum for output BN
  k_gemm<<<dim3(36, 8, 1), TPB, 0, stream>>>(
      nullptr, s_bf, Wt + (size_t)13 * NK, Wt + (size_t)13 * NK, lin_b, lin_b,
      y, y, nullptr, nullptr, nullptr, nullptr, nullptr, colsum, 1024);
  k_col_reduce<<<36, 256, 0, stream>>>(y, colsum, colsq);
  k_bn_out<<<ND_BLK, TPB, 0, stream>>>(y, colsum, colsq, bn_g, bn_b, (float*)d_out);
}

// Round 11
// 598.715 us; speedup vs baseline: 1.1320x; 1.0775x over previous
//
#include <hip/hip_runtime.h>
#include <hip/hip_bf16.h>

#define NN 4608
#define BG 48
#define NPG 96
#define DD 512
#define XDIM 16
#define EREAL 147456
#define NLAYER 6
#define NK 262144     // 512*512
#define TRIU 4656     // 96*97/2

typedef __hip_bfloat16 bf16;
typedef short short8 __attribute__((ext_vector_type(8)));
typedef short short4v __attribute__((ext_vector_type(4)));
typedef float f32x4 __attribute__((ext_vector_type(4)));

// bf16 bits (as short) -> float: shift left 16
__device__ __forceinline__ float s2f(short s) {
  return __uint_as_float(((unsigned int)(unsigned short)s) << 16);
}
__device__ __forceinline__ short f2bs(float f) {
  bf16 h = __float2bfloat16(f);
  short s;
  __builtin_memcpy(&s, &h, 2);
  return s;
}

// ---------- weight transpose + bf16 convert; also zero counts & statsAll ----------
__global__ __launch_bounds__(256) void k_wt(const float* __restrict__ wl,
                                            const float* __restrict__ wr,
                                            const float* __restrict__ cg,
                                            const float* __restrict__ lin,
                                            bf16* __restrict__ Wt,
                                            int* __restrict__ counts,
                                            float* __restrict__ statsAll) {
  if (blockIdx.z == 0) {
    int id = (blockIdx.y * 16 + blockIdx.x) * 256 + threadIdx.x;
    if (id < NN) counts[id] = 0;
    if (id < 5 * 32) statsAll[id] = 0.f;
  }
  __shared__ float tile[32][33];
  int z = blockIdx.z;
  const float* src = (z < 6) ? wl + (size_t)z * NK
                   : (z < 12) ? wr + (size_t)(z - 6) * NK
                   : (z == 12) ? cg : lin;
  bf16* dst = Wt + (size_t)z * NK;
  int c = threadIdx.x & 31;
  int r0 = threadIdx.x >> 5;  // 0..7
  int bx = blockIdx.x * 32, by = blockIdx.y * 32;
#pragma unroll
  for (int i = 0; i < 4; i++) {
    int r = r0 + i * 8;
    tile[r][c] = src[(size_t)(by + r) * 512 + bx + c];  // [k][n]
  }
  __syncthreads();
#pragma unroll
  for (int i = 0; i < 4; i++) {
    int r = r0 + i * 8;  // n within tile
    dst[(size_t)(bx + r) * 512 + by + c] = __float2bfloat16(tile[c][r]);
  }
}

// ---------- x projection + edge histogram + cloud edge params ----------
__global__ void k_xproj(const float* __restrict__ x, const float* __restrict__ w,
                        const float* __restrict__ b, const int* __restrict__ ei,
                        const float* __restrict__ xyz,
                        bf16* __restrict__ h_bf, int* __restrict__ counts,
                        float* __restrict__ ep) {
  int i = blockIdx.x * blockDim.x + threadIdx.x;
  if (i >= NN * DD) return;
  if (i < EREAL) atomicAdd(&counts[ei[EREAL + i]], 1);
  if (i < NN * NPG) {
    int n = i / NPG, e = i - n * NPG;
    int p = n % NPG;
    if (e < NPG - p) {
      int g = n / NPG;
      int slot = g * TRIU + p * NPG - (p * (p - 1)) / 2 + e;
      int j = n + e;
      float dx = xyz[n * 3] - xyz[j * 3];
      float dy = xyz[n * 3 + 1] - xyz[j * 3 + 1];
      float dz = xyz[n * 3 + 2] - xyz[j * 3 + 2];
      float sq = dx * dx + dy * dy + dz * dz;
      float dist = (sq > 0.f) ? sqrtf(sq) : 0.f;
      float4 v;
      v.x = dx; v.y = dy; v.z = dz; v.w = __expf(-dist);
      *(float4*)&ep[(size_t)slot * 4] = v;
    }
  }
  int n = i >> 9, d = i & 511;
  float acc = b[d];
#pragma unroll
  for (int k = 0; k < XDIM; k++) acc += x[n * XDIM + k] * w[k * DD + d];
  h_bf[i] = __float2bfloat16(acc);
}

// ---------- edge sort (counting sort by dst; self loops handled in gat_edge) ----------
__global__ void k_scan(const int* __restrict__ counts, int* offsets, int* cursor) {
  __shared__ int part[256];
  __shared__ int pre[256];
  int t = threadIdx.x;
  int base = t * 18;  // 4608/256
  int s = 0;
#pragma unroll
  for (int i = 0; i < 18; i++) s += counts[base + i];
  part[t] = s;
  __syncthreads();
  if (t == 0) {
    int r = 0;
    for (int i = 0; i < 256; i++) { pre[i] = r; r += part[i]; }
  }
  __syncthreads();
  int run = pre[t];
#pragma unroll
  for (int i = 0; i < 18; i++) {
    offsets[base + i] = run;
    cursor[base + i] = run;
    run += counts[base + i];
  }
  if (t == 0) offsets[NN] = EREAL;
}
__global__ void k_scatter(const int* __restrict__ ei, int* cursor, int* ssrc) {
  int e = blockIdx.x * blockDim.x + threadIdx.x;
  if (e < EREAL) {
    int s = ei[e], d = ei[EREAL + e];
    int pos = atomicAdd(&cursor[d], 1);
    ssrc[pos] = s;
  }
}

// ---------- MFMA GEMM: C[4608,512] = A_bf[4608,512] @ Wt^T + bias ----------
// statsIn != null: fused graph-LN+relu applied to A while staging.
// csum/csq != null: accumulate per-column sum/sumsq of C (for final BN).
// BM=128 BN=64 BK=32, 4 waves. blockIdx.z picks slot 0/1 (B/bias/out).
__global__ __launch_bounds__(256) void k_gemm(
    const bf16* __restrict__ Abf,
    const bf16* __restrict__ B0, const bf16* __restrict__ B1,
    const float* __restrict__ bias0, const float* __restrict__ bias1,
    float* __restrict__ C0, float* __restrict__ C1,
    bf16* __restrict__ Cb0, bf16* __restrict__ Cb1,
    const float* __restrict__ statsIn,
    const float* __restrict__ lng, const float* __restrict__ lnb,
    float* __restrict__ zptr, int zn,
    float* __restrict__ csum, float* __restrict__ csq) {
  if (zptr && blockIdx.x == 0 && blockIdx.y == 0 && blockIdx.z == 0) {
    for (int i = threadIdx.x; i < zn; i += 256) zptr[i] = 0.f;
  }
  __shared__ __align__(16) bf16 As[128 * 40];
  __shared__ __align__(16) bf16 Bs[64 * 40];
  __shared__ float cs[64], cq[64];
  const bf16* B = blockIdx.z ? B1 : B0;
  const float* bias = blockIdx.z ? bias1 : bias0;
  float* C = blockIdx.z ? C1 : C0;
  bf16* Cb = blockIdx.z ? Cb1 : Cb0;
  int tid = threadIdx.x;
  int m0 = blockIdx.x * 128, n0 = blockIdx.y * 64;
  int lane = tid & 63, wid = tid >> 6;
  int mh = (wid >> 1) * 64, nh = (wid & 1) * 32;
  int l15 = lane & 15, quad = lane >> 4;

  if (csum && tid < 64) { cs[tid] = 0.f; cq[tid] = 0.f; }

  float mu = 0.f, inv = 1.f;
  if (statsIn) {
    float s = 0.f, ss = 0.f;
#pragma unroll
    for (int i = 0; i < 16; i++) { s += statsIn[i]; ss += statsIn[16 + i]; }
    const float invM = 1.f / ((float)NN * (float)DD);
    mu = s * invM;
    float var = ss * invM - mu * mu;
    float sd = sqrtf(fmaxf(var, 0.f));
    inv = 1.f / (sd + 1e-5f);
  }

  f32x4 acc[4][2];
#pragma unroll
  for (int mt = 0; mt < 4; mt++)
#pragma unroll
    for (int nt = 0; nt < 2; nt++) acc[mt][nt] = (f32x4)0.f;

  for (int k0 = 0; k0 < 512; k0 += 32) {
    if (statsIn) {
#pragma unroll
      for (int it = 0; it < 2; it++) {
        int idx = tid + it * 256;
        int row = idx >> 2, kc = (idx & 3) * 8;
        short8 raw = *(const short8*)&Abf[(size_t)(m0 + row) * 512 + k0 + kc];
        float4 ga = *(const float4*)&lng[k0 + kc];
        float4 gb = *(const float4*)&lng[k0 + kc + 4];
        float4 ba = *(const float4*)&lnb[k0 + kc];
        float4 bb = *(const float4*)&lnb[k0 + kc + 4];
        float gg[8] = {ga.x, ga.y, ga.z, ga.w, gb.x, gb.y, gb.z, gb.w};
        float bv[8] = {ba.x, ba.y, ba.z, ba.w, bb.x, bb.y, bb.z, bb.w};
        short8 pk;
#pragma unroll
        for (int k = 0; k < 8; k++) {
          float t = fmaxf((s2f(raw[k]) - mu) * inv * gg[k] + bv[k], 0.f);
          pk[k] = f2bs(t);
        }
        *(short8*)&As[row * 40 + kc] = pk;
      }
    } else {
#pragma unroll
      for (int it = 0; it < 2; it++) {
        int idx = tid + it * 256;
        int row = idx >> 2, kc = (idx & 3) * 8;
        *(short8*)&As[row * 40 + kc] =
            *(const short8*)&Abf[(size_t)(m0 + row) * 512 + k0 + kc];
      }
    }
    {
      int row = tid >> 2, kc = (tid & 3) * 8;
      *(short8*)&Bs[row * 40 + kc] =
          *(const short8*)&B[(size_t)(n0 + row) * 512 + k0 + kc];
    }
    __syncthreads();
    short8 af[4], bfr[2];
#pragma unroll
    for (int mt = 0; mt < 4; mt++)
      af[mt] = *(const short8*)&As[(mh + mt * 16 + l15) * 40 + quad * 8];
#pragma unroll
    for (int nt = 0; nt < 2; nt++)
      bfr[nt] = *(const short8*)&Bs[(nh + nt * 16 + l15) * 40 + quad * 8];
#pragma unroll
    for (int mt = 0; mt < 4; mt++)
#pragma unroll
      for (int nt = 0; nt < 2; nt++)
        acc[mt][nt] = __builtin_amdgcn_mfma_f32_16x16x32_bf16(
            af[mt], bfr[nt], acc[mt][nt], 0, 0, 0);
    __syncthreads();
  }
  float colS[2] = {0.f, 0.f}, colQ[2] = {0.f, 0.f};
#pragma unroll
  for (int mt = 0; mt < 4; mt++) {
#pragma unroll
    for (int nt = 0; nt < 2; nt++) {
      int col = n0 + nh + nt * 16 + l15;
      float bv = bias ? bias[col] : 0.f;
#pragma unroll
      for (int r = 0; r < 4; r++) {
        int row = m0 + mh + mt * 16 + quad * 4 + r;
        float v = acc[mt][nt][r] + bv;
        if (C) C[(size_t)row * 512 + col] = v;
        if (Cb) Cb[(size_t)row * 512 + col] = __float2bfloat16(v);
        if (csum) { colS[nt] += v; colQ[nt] += v * v; }
      }
    }
  }
  if (csum) {
#pragma unroll
    for (int nt = 0; nt < 2; nt++) {
      atomicAdd(&cs[nh + nt * 16 + l15], colS[nt]);
      atomicAdd(&cq[nh + nt * 16 + l15], colQ[nt]);
    }
    __syncthreads();
    if (tid < 64) {
      atomicAdd(&csum[n0 + tid], cs[tid]);
      atomicAdd(&csq[n0 + tid], cq[tid]);
    }
  }
}

// ---------- GAT edge + softmax (fixed self-score offset) + aggregate + LN stats ----
// One wave per dst node; lane owns 8 contiguous dims; bf16 in, bf16 out.
__global__ __launch_bounds__(256) void k_gat_edge(const bf16* __restrict__ xl,
                                                  const bf16* __restrict__ xr,
                                                  const float* __restrict__ att,
                                                  const float* __restrict__ bias,
                                                  const int* __restrict__ offs,
                                                  const int* __restrict__ ssrc,
                                                  bf16* __restrict__ out,
                                                  float* __restrict__ statsOut) {
  __shared__ float redS[4], redSS[4];
  int wave = (blockIdx.x * blockDim.x + threadIdx.x) >> 6;
  int lane = threadIdx.x & 63;
  int wid = threadIdx.x >> 6;
  if (wave < NN) {
    int n = wave;
    int base = lane * 8;
    float xrv[8], attv[8], acc[8];
    short8 xr8 = *(const short8*)&xr[(size_t)n * 512 + base];
#pragma unroll
    for (int k = 0; k < 8; k++) {
      xrv[k] = s2f(xr8[k]);
      attv[k] = att[base + k];
    }
    // self edge: offset m0 = score(n,n); p_self = 1
    float m0, lsum;
    {
      short8 a8 = *(const short8*)&xl[(size_t)n * 512 + base];
      float sc0 = 0.f;
#pragma unroll
      for (int k = 0; k < 8; k++) {
        float v = s2f(a8[k]);
        acc[k] = v;
        float t = v + xrv[k];
        t = (t > 0.f) ? t : 0.2f * t;
        sc0 += attv[k] * t;
      }
#pragma unroll
      for (int off = 32; off >= 1; off >>= 1) sc0 += __shfl_xor(sc0, off, 64);
      m0 = sc0;
      lsum = 1.f;
    }
    int e0 = offs[n], e1 = offs[n + 1];
    int e = e0;
    for (; e + 3 < e1; e += 4) {
      int s0 = ssrc[e], s1 = ssrc[e + 1], s2 = ssrc[e + 2], s3 = ssrc[e + 3];
      short8 a0 = *(const short8*)&xl[(size_t)s0 * 512 + base];
      short8 a1 = *(const short8*)&xl[(size_t)s1 * 512 + base];
      short8 a2 = *(const short8*)&xl[(size_t)s2 * 512 + base];
      short8 a3 = *(const short8*)&xl[(size_t)s3 * 512 + base];
      float x0[8], x1[8], x2[8], x3[8];
      float c0 = 0.f, c1 = 0.f, c2 = 0.f, c3 = 0.f;
#pragma unroll
      for (int k = 0; k < 8; k++) {
        float v0 = s2f(a0[k]), v1 = s2f(a1[k]), v2 = s2f(a2[k]), v3 = s2f(a3[k]);
        x0[k] = v0; x1[k] = v1; x2[k] = v2; x3[k] = v3;
        float t0 = v0 + xrv[k]; t0 = (t0 > 0.f) ? t0 : 0.2f * t0; c0 += attv[k] * t0;
        float t1 = v1 + xrv[k]; t1 = (t1 > 0.f) ? t1 : 0.2f * t1; c1 += attv[k] * t1;
        float t2 = v2 + xrv[k]; t2 = (t2 > 0.f) ? t2 : 0.2f * t2; c2 += attv[k] * t2;
        float t3 = v3 + xrv[k]; t3 = (t3 > 0.f) ? t3 : 0.2f * t3; c3 += attv[k] * t3;
      }
#pragma unroll
      for (int off = 32; off >= 1; off >>= 1) {
        c0 += __shfl_xor(c0, off, 64);
        c1 += __shfl_xor(c1, off, 64);
        c2 += __shfl_xor(c2, off, 64);
        c3 += __shfl_xor(c3, off, 64);
      }
      float p0 = __expf(c0 - m0), p1 = __expf(c1 - m0);
      float p2 = __expf(c2 - m0), p3 = __expf(c3 - m0);
      lsum += p0 + p1 + p2 + p3;
#pragma unroll
      for (int k = 0; k < 8; k++)
        acc[k] += p0 * x0[k] + p1 * x1[k] + p2 * x2[k] + p3 * x3[k];
    }
    for (; e < e1; ++e) {
      int s0 = ssrc[e];
      short8 a8 = *(const short8*)&xl[(size_t)s0 * 512 + base];
      float x0[8];
      float sc0 = 0.f;
#pragma unroll
      for (int k = 0; k < 8; k++) {
        float v0 = s2f(a8[k]);
        x0[k] = v0;
        float t0 = v0 + xrv[k];
        t0 = (t0 > 0.f) ? t0 : 0.2f * t0;
        sc0 += attv[k] * t0;
      }
#pragma unroll
      for (int off = 32; off >= 1; off >>= 1) sc0 += __shfl_xor(sc0, off, 64);
      float p0 = __expf(sc0 - m0);
      lsum += p0;
#pragma unroll
      for (int k = 0; k < 8; k++) acc[k] += p0 * x0[k];
    }
    float inv = 1.f / lsum;
    float o[8];
    float s = 0.f, ss = 0.f;
    short8 o8;
#pragma unroll
    for (int k = 0; k < 8; k++) {
      o[k] = acc[k] * inv + bias[base + k];
      s += o[k];
      ss += o[k] * o[k];
      o8[k] = f2bs(o[k]);
    }
    *(short8*)&out[(size_t)n * 512 + base] = o8;
    if (statsOut) {
#pragma unroll
      for (int off = 32; off >= 1; off >>= 1) {
        s += __shfl_xor(s, off, 64);
        ss += __shfl_xor(ss, off, 64);
      }
      if (lane == 0) { redS[wid] = s; redSS[wid] = ss; }
    }
  }
  if (statsOut) {
    __syncthreads();
    if (threadIdx.x == 0) {
      float a = redS[0] + redS[1] + redS[2] + redS[3];
      float b = redSS[0] + redSS[1] + redSS[2] + redSS[3];
      int slot = blockIdx.x & 15;
      atomicAdd(&statsOut[slot], a);
      atomicAdd(&statsOut[16 + slot], b);
    }
  }
}

// ---------- CloudGraph: balanced — wave handles node pair (p, 95-p), 97 edges ----
__global__ __launch_bounds__(256) void k_cloud(const bf16* __restrict__ g1,
                                               const float* __restrict__ ep,
                                               const float* __restrict__ lin1b,
                                               const float* __restrict__ w3,
                                               float* __restrict__ p1,
                                               float* __restrict__ p2) {
  int w = (blockIdx.x * blockDim.x + threadIdx.x) >> 6;
  int lane = threadIdx.x & 63;
  if (w >= NN) return;
  int hf = w & 1;
  int pi = w >> 1;              // [0, 2304)
  int g = pi / 48, pp = pi % 48;
  int d0 = hf * 256 + lane * 4;
  float4 bb = *(const float4*)&lin1b[d0];
  float4 w30 = *(const float4*)&w3[d0];
  float4 w31 = *(const float4*)&w3[512 + d0];
  float4 w32 = *(const float4*)&w3[1024 + d0];
  float bbv[4] = {bb.x, bb.y, bb.z, bb.w};
  float w0v[4] = {w30.x, w30.y, w30.z, w30.w};
  float w1v[4] = {w31.x, w31.y, w31.z, w31.w};
  float w2v[4] = {w32.x, w32.y, w32.z, w32.w};

#pragma unroll
  for (int half = 0; half < 2; half++) {
    int p = half ? (NPG - 1 - pp) : pp;
    int n = g * NPG + p;
    int cnt = NPG - p;
    int slot0 = g * TRIU + p * NPG - (p * (p - 1)) / 2;
    float gi[4], a1[4], a2[4];
    short4v gi4 = *(const short4v*)&g1[(size_t)n * 512 + d0];
#pragma unroll
    for (int k = 0; k < 4; k++) {
      gi[k] = s2f(gi4[k]);
      a1[k] = 0.f;
      a2[k] = 0.f;
    }
    int e = 0;
    for (; e + 1 < cnt; e += 2) {
      float4 pa = *(const float4*)&ep[(size_t)(slot0 + e) * 4];
      float4 pb = *(const float4*)&ep[(size_t)(slot0 + e + 1) * 4];
      short4v ga = *(const short4v*)&g1[(size_t)(n + e) * 512 + d0];
      short4v gb = *(const short4v*)&g1[(size_t)(n + e + 1) * 512 + d0];
#pragma unroll
      for (int k = 0; k < 4; k++) {
        float t = fmaf(pa.w, gi[k] - s2f(ga[k]), bbv[k]);
        a1[k] += fmaxf(t, 0.f);
        float u = fmaf(pb.w, gi[k] - s2f(gb[k]), bbv[k]);
        a1[k] += fmaxf(u, 0.f);
        float t2 = pa.x * w0v[k] + pa.y * w1v[k] + pa.z * w2v[k];
        a2[k] += fmaxf(t2, 0.f);
        float u2 = pb.x * w0v[k] + pb.y * w1v[k] + pb.z * w2v[k];
        a2[k] += fmaxf(u2, 0.f);
      }
    }
    if (e < cnt) {
      float4 pa = *(const float4*)&ep[(size_t)(slot0 + e) * 4];
      short4v ga = *(const short4v*)&g1[(size_t)(n + e) * 512 + d0];
#pragma unroll
      for (int k = 0; k < 4; k++) {
        float t = fmaf(pa.w, gi[k] - s2f(ga[k]), bbv[k]);
        a1[k] += fmaxf(t, 0.f);
        float t2 = pa.x * w0v[k] + pa.y * w1v[k] + pa.z * w2v[k];
        a2[k] += fmaxf(t2, 0.f);
      }
    }
    float4 o1, o2;
    o1.x = a1[0]; o1.y = a1[1]; o1.z = a1[2]; o1.w = a1[3];
    o2.x = a2[0]; o2.y = a2[1]; o2.z = a2[2]; o2.w = a2[3];
    *(float4*)&p1[(size_t)n * 512 + d0] = o1;
    *(float4*)&p2[(size_t)n * 512 + d0] = o2;
  }
}

// ---------- fused cloud epilogue: ln_row(p1) + bn(p2) + fuse -> s_bf ----------
// Also zeroes colsum2/colsq2 (1024 floats) for the final GEMM's column stats.
__global__ __launch_bounds__(256) void k_cloud_epi(
    const float* __restrict__ p1, const float* __restrict__ p2,
    const bf16* __restrict__ h_bf, const bf16* __restrict__ xg_bf,
    const float* __restrict__ colsum, const float* __restrict__ colsq,
    const float* __restrict__ lng, const float* __restrict__ lnb,
    const float* __restrict__ bng, const float* __restrict__ bnb,
    bf16* __restrict__ s_bf, float* __restrict__ zptr) {
  if (blockIdx.x == 0) {
    for (int i = threadIdx.x; i < 1024; i += 256) zptr[i] = 0.f;
  }
  int wave = (blockIdx.x * blockDim.x + threadIdx.x) >> 6;
  int lane = threadIdx.x & 63;
  if (wave >= NN) return;
  int n = wave;
  size_t rb = (size_t)n * 512 + lane * 8;
  int base = lane * 8;
  float v[8];
  float s = 0.f;
#pragma unroll
  for (int k = 0; k < 8; k++) {
    v[k] = p1[rb + k];
    s += v[k];
  }
#pragma unroll
  for (int off = 32; off >= 1; off >>= 1) s += __shfl_xor(s, off, 64);
  float mu = s * (1.f / 512.f);
  float ss = 0.f;
#pragma unroll
  for (int k = 0; k < 8; k++) {
    float t = v[k] - mu;
    ss += t * t;
  }
#pragma unroll
  for (int off = 32; off >= 1; off >>= 1) ss += __shfl_xor(ss, off, 64);
  float inv = 1.f / sqrtf(ss * (1.f / 512.f) + 1e-5f);
  short8 hb = *(const short8*)&h_bf[rb];
  short8 xb = *(const short8*)&xg_bf[rb];
  short8 o8;
#pragma unroll
  for (int k = 0; k < 8; k++) {
    int d = base + k;
    float ln1 = (v[k] - mu) * inv * lng[d] + lnb[d];
    float cmu = colsum[d] * (1.f / NN);
    float cvar = colsq[d] * (1.f / NN) - cmu * cmu;
    float cinv = 1.f / sqrtf(fmaxf(cvar, 0.f) + 1e-5f);
    float bnv = (p2[rb + k] - cmu) * cinv * bng[d] + bnb[d];
    float out = 2.f * s2f(hb[k]) + s2f(xb[k]) + ln1 + bnv;
    o8[k] = f2bs(out);
  }
  *(short8*)&s_bf[rb] = o8;
}

// ---------- column (batchnorm) stats (used for p2 only) ----------
__global__ void k_col_reduce(const float* __restrict__ x, float* colsum, float* colsq) {
  int r0 = blockIdx.x * 128;
  int c0 = threadIdx.x;
  float s0 = 0.f, q0 = 0.f, s1 = 0.f, q1 = 0.f;
  for (int r = r0; r < r0 + 128; ++r) {
    float v = x[(size_t)r * 512 + c0];
    s0 += v;
    q0 += v * v;
    float w = x[(size_t)r * 512 + c0 + 256];
    s1 += w;
    q1 += w * w;
  }
  atomicAdd(&colsum[c0], s0);
  atomicAdd(&colsq[c0], q0);
  atomicAdd(&colsum[c0 + 256], s1);
  atomicAdd(&colsq[c0 + 256], q1);
}
__global__ void k_bn_out(const float* __restrict__ y, const float* __restrict__ colsum,
                         const float* __restrict__ colsq, const float* __restrict__ g,
                         const float* __restrict__ b, float* __restrict__ out) {
  int i = blockIdx.x * blockDim.x + threadIdx.x;
  if (i >= NN * DD) return;
  int d = i & 511;
  float mu = colsum[d] * (1.f / NN);
  float var = colsq[d] * (1.f / NN) - mu * mu;
  float inv = 1.f / sqrtf(fmaxf(var, 0.f) + 1e-5f);
  out[i] = (y[i] - mu) * inv * g[d] + b[d];
}

extern "C" void kernel_launch(void* const* d_in, const int* in_sizes, int n_in,
                              void* d_out, int out_size, void* d_ws, size_t ws_size,
                              hipStream_t stream) {
  const float* x = (const float*)d_in[0];
  const int* ei = (const int*)d_in[1];
  const float* xyz = (const float*)d_in[3];
  const float* x_proj_w = (const float*)d_in[5];
  const float* x_proj_b = (const float*)d_in[6];
  const float* gat_wl = (const float*)d_in[7];
  const float* gat_bl = (const float*)d_in[8];
  const float* gat_wr = (const float*)d_in[9];
  const float* gat_br = (const float*)d_in[10];
  const float* gat_att = (const float*)d_in[11];
  const float* gat_bias = (const float*)d_in[12];
  const float* gat_ln_g = (const float*)d_in[13];
  const float* gat_ln_b = (const float*)d_in[14];
  const float* cg_xyz_w = (const float*)d_in[15];
  const float* cg_bn_g = (const float*)d_in[16];
  const float* cg_bn_b = (const float*)d_in[17];
  const float* cg_lin1_w = (const float*)d_in[18];
  const float* cg_lin1_b = (const float*)d_in[19];
  const float* cg_ln_g = (const float*)d_in[20];
  const float* cg_ln_b = (const float*)d_in[21];
  const float* lin_w = (const float*)d_in[22];
  const float* lin_b = (const float*)d_in[23];
  const float* bn_g = (const float*)d_in[24];
  const float* bn_b = (const float*)d_in[25];

  const size_t ND = (size_t)NN * DD;
  char* w = (char*)d_ws;
  float* p1 = (float*)w;       w += ND * 4;  // alias: final y
  float* p2 = (float*)w;       w += ND * 4;
  bf16* h_bf = (bf16*)w;       w += ND * 2;  // alias: s_bf (after cloud GEMM)
  bf16* xg_bf = (bf16*)w;      w += ND * 2;
  bf16* xl_bf = (bf16*)w;      w += ND * 2;  // alias: g1_bf (after GAT)
  bf16* xr_bf = (bf16*)w;      w += ND * 2;
  bf16* Wt = (bf16*)w;         w += (size_t)14 * NK * 2;
  float* eparam = (float*)w;   w += (size_t)BG * TRIU * 16;
  int* counts = (int*)w;       w += NN * 4;
  int* offs = (int*)w;         w += (NN + 4) * 4;
  int* cursor = (int*)w;       w += NN * 4;
  int* ssrc = (int*)w;         w += EREAL * 4;
  float* statsAll = (float*)w; w += 5 * 32 * 4;
  float* colsum = (float*)w;   w += 512 * 4;
  float* colsq = (float*)w;    w += 512 * 4;
  float* colsum2 = (float*)w;  w += 512 * 4;
  float* colsq2 = (float*)w;   w += 512 * 4;
  float* y = p1;
  bf16* g1_bf = xl_bf;
  bf16* s_bf = h_bf;

  const int TPB = 256;
  const int ND_BLK = (int)((ND + TPB - 1) / TPB);

  k_wt<<<dim3(16, 16, 14), TPB, 0, stream>>>(gat_wl, gat_wr, cg_lin1_w, lin_w, Wt,
                                             counts, statsAll);
  k_xproj<<<ND_BLK, TPB, 0, stream>>>(x, x_proj_w, x_proj_b, ei, xyz, h_bf,
                                      counts, eparam);
  k_scan<<<1, 256, 0, stream>>>(counts, offs, cursor);
  k_scatter<<<(EREAL + TPB - 1) / TPB, TPB, 0, stream>>>(ei, cursor, ssrc);

  for (int l = 0; l < NLAYER; l++) {
    const bf16* A = (l == 0) ? h_bf : xg_bf;
    const float* sIn = (l > 0) ? statsAll + 32 * (l - 1) : nullptr;
    const float* lg = (l > 0) ? gat_ln_g + (l - 1) * DD : nullptr;
    const float* lb = (l > 0) ? gat_ln_b + (l - 1) * DD : nullptr;
    k_gemm<<<dim3(36, 8, 2), TPB, 0, stream>>>(
        A, Wt + (size_t)l * NK, Wt + (size_t)(6 + l) * NK,
        gat_bl + l * DD, gat_br + l * DD, nullptr, nullptr, xl_bf, xr_bf,
        sIn, lg, lb, nullptr, 0, nullptr, nullptr);
    float* sOut = (l < NLAYER - 1) ? statsAll + 32 * l : nullptr;
    k_gat_edge<<<NN / 4, TPB, 0, stream>>>(xl_bf, xr_bf, gat_att + l * DD,
                                           gat_bias + l * DD, offs, ssrc,
                                           xg_bf, sOut);
  }

  // CloudGraph: g1 = h @ cg_lin1_w (no bias), bf16 out; zero colsum for p2 BN
  k_gemm<<<dim3(36, 8, 1), TPB, 0, stream>>>(
      h_bf, Wt + (size_t)12 * NK, Wt + (size_t)12 * NK, nullptr, nullptr,
      nullptr, nullptr, g1_bf, g1_bf, nullptr, nullptr, nullptr,
      colsum, 1024, nullptr, nullptr);
  k_cloud<<<NN / 4, TPB, 0, stream>>>(g1_bf, eparam, cg_lin1_b, cg_xyz_w, p1, p2);
  k_col_reduce<<<36, 256, 0, stream>>>(p2, colsum, colsq);
  k_cloud_epi<<<NN / 4, TPB, 0, stream>>>(p1, p2, h_bf, xg_bf, colsum, colsq,
                                          cg_ln_g, cg_ln_b, cg_bn_g, cg_bn_b,
                                          s_bf, colsum2);

  // final: y = s @ lin_w + lin_b (fp32) with fused column stats -> bn_out
  k_gemm<<<dim3(36, 8, 1), TPB, 0, stream>>>(
      s_bf, Wt + (size_t)13 * NK, Wt + (size_t)13 * NK, lin_b, lin_b,
      y, y, nullptr, nullptr, nullptr, nullptr, nullptr,
      nullptr, 0, colsum2, colsq2);
  k_bn_out<<<ND_BLK, TPB, 0, stream>>>(y, colsum2, colsq2, bn_g, bn_b,
                                       (float*)d_out);
}

// Round 12
// 597.762 us; speedup vs baseline: 1.1338x; 1.0016x over previous
//
#include <hip/hip_runtime.h>
#include <hip/hip_bf16.h>

#define NN 4608
#define BG 48
#define NPG 96
#define DD 512
#define XDIM 16
#define EREAL 147456
#define NLAYER 6
#define NK 262144     // 512*512
#define TRIU 4656     // 96*97/2

typedef __hip_bfloat16 bf16;
typedef short short8 __attribute__((ext_vector_type(8)));
typedef float f32x4 __attribute__((ext_vector_type(4)));
typedef float f32x2 __attribute__((ext_vector_type(2)));

// bf16 bits (as short) -> float: shift left 16
__device__ __forceinline__ float s2f(short s) {
  return __uint_as_float(((unsigned int)(unsigned short)s) << 16);
}
__device__ __forceinline__ short f2bs(float f) {
  bf16 h = __float2bfloat16(f);
  short s;
  __builtin_memcpy(&s, &h, 2);
  return s;
}
// fp8 e4m3 byte from float
__device__ __forceinline__ unsigned char f2f8(float v) {
  return (unsigned char)(__builtin_amdgcn_cvt_pk_fp8_f32(v, v, 0, false) & 0xff);
}
// decode 4 fp8 bytes (one dword) -> 4 floats
__device__ __forceinline__ void f8x4(unsigned int w, float* o) {
  f32x2 a = __builtin_amdgcn_cvt_pk_f32_fp8(w, false);
  f32x2 b = __builtin_amdgcn_cvt_pk_f32_fp8(w, true);
  o[0] = a[0]; o[1] = a[1]; o[2] = b[0]; o[3] = b[1];
}

// ---------- weight transpose + bf16 convert; also zero counts & statsAll ----------
__global__ __launch_bounds__(256) void k_wt(const float* __restrict__ wl,
                                            const float* __restrict__ wr,
                                            const float* __restrict__ cg,
                                            const float* __restrict__ lin,
                                            bf16* __restrict__ Wt,
                                            int* __restrict__ counts,
                                            float* __restrict__ statsAll) {
  if (blockIdx.z == 0) {
    int id = (blockIdx.y * 16 + blockIdx.x) * 256 + threadIdx.x;
    if (id < NN) counts[id] = 0;
    if (id < 5 * 32) statsAll[id] = 0.f;
  }
  __shared__ float tile[32][33];
  int z = blockIdx.z;
  const float* src = (z < 6) ? wl + (size_t)z * NK
                   : (z < 12) ? wr + (size_t)(z - 6) * NK
                   : (z == 12) ? cg : lin;
  bf16* dst = Wt + (size_t)z * NK;
  int c = threadIdx.x & 31;
  int r0 = threadIdx.x >> 5;  // 0..7
  int bx = blockIdx.x * 32, by = blockIdx.y * 32;
#pragma unroll
  for (int i = 0; i < 4; i++) {
    int r = r0 + i * 8;
    tile[r][c] = src[(size_t)(by + r) * 512 + bx + c];  // [k][n]
  }
  __syncthreads();
#pragma unroll
  for (int i = 0; i < 4; i++) {
    int r = r0 + i * 8;  // n within tile
    dst[(size_t)(bx + r) * 512 + by + c] = __float2bfloat16(tile[c][r]);
  }
}

// ---------- x projection + edge histogram + cloud edge params ----------
__global__ void k_xproj(const float* __restrict__ x, const float* __restrict__ w,
                        const float* __restrict__ b, const int* __restrict__ ei,
                        const float* __restrict__ xyz,
                        bf16* __restrict__ h_bf, int* __restrict__ counts,
                        float* __restrict__ ep) {
  int i = blockIdx.x * blockDim.x + threadIdx.x;
  if (i >= NN * DD) return;
  if (i < EREAL) atomicAdd(&counts[ei[EREAL + i]], 1);
  if (i < NN * NPG) {
    int n = i / NPG, e = i - n * NPG;
    int p = n % NPG;
    if (e < NPG - p) {
      int g = n / NPG;
      int slot = g * TRIU + p * NPG - (p * (p - 1)) / 2 + e;
      int j = n + e;
      float dx = xyz[n * 3] - xyz[j * 3];
      float dy = xyz[n * 3 + 1] - xyz[j * 3 + 1];
      float dz = xyz[n * 3 + 2] - xyz[j * 3 + 2];
      float sq = dx * dx + dy * dy + dz * dz;
      float dist = (sq > 0.f) ? sqrtf(sq) : 0.f;
      float4 v;
      v.x = dx; v.y = dy; v.z = dz; v.w = __expf(-dist);
      *(float4*)&ep[(size_t)slot * 4] = v;
    }
  }
  int n = i >> 9, d = i & 511;
  float acc = b[d];
#pragma unroll
  for (int k = 0; k < XDIM; k++) acc += x[n * XDIM + k] * w[k * DD + d];
  h_bf[i] = __float2bfloat16(acc);
}

// ---------- edge sort (counting sort by dst; self loops handled in gat_edge) ----------
__global__ void k_scan(const int* __restrict__ counts, int* offsets, int* cursor) {
  __shared__ int part[256];
  __shared__ int pre[256];
  int t = threadIdx.x;
  int base = t * 18;  // 4608/256
  int s = 0;
#pragma unroll
  for (int i = 0; i < 18; i++) s += counts[base + i];
  part[t] = s;
  __syncthreads();
  if (t == 0) {
    int r = 0;
    for (int i = 0; i < 256; i++) { pre[i] = r; r += part[i]; }
  }
  __syncthreads();
  int run = pre[t];
#pragma unroll
  for (int i = 0; i < 18; i++) {
    offsets[base + i] = run;
    cursor[base + i] = run;
    run += counts[base + i];
  }
  if (t == 0) offsets[NN] = EREAL;
}
__global__ void k_scatter(const int* __restrict__ ei, int* cursor, int* ssrc) {
  int e = blockIdx.x * blockDim.x + threadIdx.x;
  if (e < EREAL) {
    int s = ei[e], d = ei[EREAL + e];
    int pos = atomicAdd(&cursor[d], 1);
    ssrc[pos] = s;
  }
}

// ---------- MFMA GEMM: C[4608,512] = A_bf[4608,512] @ Wt^T + bias ----------
// statsIn != null: fused graph-LN+relu applied to A while staging.
// csum/csq != null: accumulate per-column sum/sumsq of C (final BN).
// Cf8: optional fp8 e4m3 output. blockIdx.z picks slot 0/1.
__global__ __launch_bounds__(256) void k_gemm(
    const bf16* __restrict__ Abf,
    const bf16* __restrict__ B0, const bf16* __restrict__ B1,
    const float* __restrict__ bias0, const float* __restrict__ bias1,
    float* __restrict__ C0, float* __restrict__ C1,
    bf16* __restrict__ Cb0, bf16* __restrict__ Cb1,
    unsigned char* __restrict__ Cf8_0, unsigned char* __restrict__ Cf8_1,
    const float* __restrict__ statsIn,
    const float* __restrict__ lng, const float* __restrict__ lnb,
    float* __restrict__ zptr, int zn,
    float* __restrict__ csum, float* __restrict__ csq) {
  if (zptr && blockIdx.x == 0 && blockIdx.y == 0 && blockIdx.z == 0) {
    for (int i = threadIdx.x; i < zn; i += 256) zptr[i] = 0.f;
  }
  __shared__ __align__(16) bf16 As[128 * 40];
  __shared__ __align__(16) bf16 Bs[64 * 40];
  __shared__ float cs[64], cq[64];
  const bf16* B = blockIdx.z ? B1 : B0;
  const float* bias = blockIdx.z ? bias1 : bias0;
  float* C = blockIdx.z ? C1 : C0;
  bf16* Cb = blockIdx.z ? Cb1 : Cb0;
  unsigned char* Cf8 = blockIdx.z ? Cf8_1 : Cf8_0;
  int tid = threadIdx.x;
  int m0 = blockIdx.x * 128, n0 = blockIdx.y * 64;
  int lane = tid & 63, wid = tid >> 6;
  int mh = (wid >> 1) * 64, nh = (wid & 1) * 32;
  int l15 = lane & 15, quad = lane >> 4;

  if (csum && tid < 64) { cs[tid] = 0.f; cq[tid] = 0.f; }

  float mu = 0.f, inv = 1.f;
  if (statsIn) {
    float s = 0.f, ss = 0.f;
#pragma unroll
    for (int i = 0; i < 16; i++) { s += statsIn[i]; ss += statsIn[16 + i]; }
    const float invM = 1.f / ((float)NN * (float)DD);
    mu = s * invM;
    float var = ss * invM - mu * mu;
    float sd = sqrtf(fmaxf(var, 0.f));
    inv = 1.f / (sd + 1e-5f);
  }

  f32x4 acc[4][2];
#pragma unroll
  for (int mt = 0; mt < 4; mt++)
#pragma unroll
    for (int nt = 0; nt < 2; nt++) acc[mt][nt] = (f32x4)0.f;

  for (int k0 = 0; k0 < 512; k0 += 32) {
    if (statsIn) {
#pragma unroll
      for (int it = 0; it < 2; it++) {
        int idx = tid + it * 256;
        int row = idx >> 2, kc = (idx & 3) * 8;
        short8 raw = *(const short8*)&Abf[(size_t)(m0 + row) * 512 + k0 + kc];
        float4 ga = *(const float4*)&lng[k0 + kc];
        float4 gb = *(const float4*)&lng[k0 + kc + 4];
        float4 ba = *(const float4*)&lnb[k0 + kc];
        float4 bb = *(const float4*)&lnb[k0 + kc + 4];
        float gg[8] = {ga.x, ga.y, ga.z, ga.w, gb.x, gb.y, gb.z, gb.w};
        float bv[8] = {ba.x, ba.y, ba.z, ba.w, bb.x, bb.y, bb.z, bb.w};
        short8 pk;
#pragma unroll
        for (int k = 0; k < 8; k++) {
          float t = fmaxf((s2f(raw[k]) - mu) * inv * gg[k] + bv[k], 0.f);
          pk[k] = f2bs(t);
        }
        *(short8*)&As[row * 40 + kc] = pk;
      }
    } else {
#pragma unroll
      for (int it = 0; it < 2; it++) {
        int idx = tid + it * 256;
        int row = idx >> 2, kc = (idx & 3) * 8;
        *(short8*)&As[row * 40 + kc] =
            *(const short8*)&Abf[(size_t)(m0 + row) * 512 + k0 + kc];
      }
    }
    {
      int row = tid >> 2, kc = (tid & 3) * 8;
      *(short8*)&Bs[row * 40 + kc] =
          *(const short8*)&B[(size_t)(n0 + row) * 512 + k0 + kc];
    }
    __syncthreads();
    short8 af[4], bfr[2];
#pragma unroll
    for (int mt = 0; mt < 4; mt++)
      af[mt] = *(const short8*)&As[(mh + mt * 16 + l15) * 40 + quad * 8];
#pragma unroll
    for (int nt = 0; nt < 2; nt++)
      bfr[nt] = *(const short8*)&Bs[(nh + nt * 16 + l15) * 40 + quad * 8];
#pragma unroll
    for (int mt = 0; mt < 4; mt++)
#pragma unroll
      for (int nt = 0; nt < 2; nt++)
        acc[mt][nt] = __builtin_amdgcn_mfma_f32_16x16x32_bf16(
            af[mt], bfr[nt], acc[mt][nt], 0, 0, 0);
    __syncthreads();
  }
  float colS[2] = {0.f, 0.f}, colQ[2] = {0.f, 0.f};
#pragma unroll
  for (int mt = 0; mt < 4; mt++) {
#pragma unroll
    for (int nt = 0; nt < 2; nt++) {
      int col = n0 + nh + nt * 16 + l15;
      float bv = bias ? bias[col] : 0.f;
#pragma unroll
      for (int r = 0; r < 4; r++) {
        int row = m0 + mh + mt * 16 + quad * 4 + r;
        float v = acc[mt][nt][r] + bv;
        if (C) C[(size_t)row * 512 + col] = v;
        if (Cb) Cb[(size_t)row * 512 + col] = __float2bfloat16(v);
        if (Cf8) Cf8[(size_t)row * 512 + col] = f2f8(v);
        if (csum) { colS[nt] += v; colQ[nt] += v * v; }
      }
    }
  }
  if (csum) {
#pragma unroll
    for (int nt = 0; nt < 2; nt++) {
      atomicAdd(&cs[nh + nt * 16 + l15], colS[nt]);
      atomicAdd(&cq[nh + nt * 16 + l15], colQ[nt]);
    }
    __syncthreads();
    if (tid < 64) {
      atomicAdd(&csum[n0 + tid], cs[tid]);
      atomicAdd(&csq[n0 + tid], cq[tid]);
    }
  }
}

// ---------- GAT edge + softmax (fixed self-score offset) + aggregate + LN stats ----
// One wave per dst node; lane owns 8 contiguous dims; xl in fp8 (8B gathers).
__global__ __launch_bounds__(256) void k_gat_edge(const unsigned char* __restrict__ xl8,
                                                  const bf16* __restrict__ xr,
                                                  const float* __restrict__ att,
                                                  const float* __restrict__ bias,
                                                  const int* __restrict__ offs,
                                                  const int* __restrict__ ssrc,
                                                  bf16* __restrict__ out,
                                                  float* __restrict__ statsOut) {
  __shared__ float redS[4], redSS[4];
  int wave = (blockIdx.x * blockDim.x + threadIdx.x) >> 6;
  int lane = threadIdx.x & 63;
  int wid = threadIdx.x >> 6;
  if (wave < NN) {
    int n = wave;
    int base = lane * 8;
    float xrv[8], attv[8], acc[8];
    short8 xr8 = *(const short8*)&xr[(size_t)n * 512 + base];
#pragma unroll
    for (int k = 0; k < 8; k++) {
      xrv[k] = s2f(xr8[k]);
      attv[k] = att[base + k];
    }
    // self edge: offset m0 = score(n,n); p_self = 1
    float m0, lsum;
    {
      uint2 q = *(const uint2*)&xl8[(size_t)n * 512 + base];
      float xs[8];
      f8x4(q.x, xs);
      f8x4(q.y, xs + 4);
      float sc0 = 0.f;
#pragma unroll
      for (int k = 0; k < 8; k++) {
        acc[k] = xs[k];
        float t = xs[k] + xrv[k];
        t = (t > 0.f) ? t : 0.2f * t;
        sc0 += attv[k] * t;
      }
#pragma unroll
      for (int off = 32; off >= 1; off >>= 1) sc0 += __shfl_xor(sc0, off, 64);
      m0 = sc0;
      lsum = 1.f;
    }
    int e0 = offs[n], e1 = offs[n + 1];
    int e = e0;
    for (; e + 3 < e1; e += 4) {
      int s0 = ssrc[e], s1 = ssrc[e + 1], s2 = ssrc[e + 2], s3 = ssrc[e + 3];
      uint2 q0 = *(const uint2*)&xl8[(size_t)s0 * 512 + base];
      uint2 q1 = *(const uint2*)&xl8[(size_t)s1 * 512 + base];
      uint2 q2 = *(const uint2*)&xl8[(size_t)s2 * 512 + base];
      uint2 q3 = *(const uint2*)&xl8[(size_t)s3 * 512 + base];
      float x0[8], x1[8], x2[8], x3[8];
      f8x4(q0.x, x0); f8x4(q0.y, x0 + 4);
      f8x4(q1.x, x1); f8x4(q1.y, x1 + 4);
      f8x4(q2.x, x2); f8x4(q2.y, x2 + 4);
      f8x4(q3.x, x3); f8x4(q3.y, x3 + 4);
      float c0 = 0.f, c1 = 0.f, c2 = 0.f, c3 = 0.f;
#pragma unroll
      for (int k = 0; k < 8; k++) {
        float t0 = x0[k] + xrv[k]; t0 = (t0 > 0.f) ? t0 : 0.2f * t0; c0 += attv[k] * t0;
        float t1 = x1[k] + xrv[k]; t1 = (t1 > 0.f) ? t1 : 0.2f * t1; c1 += attv[k] * t1;
        float t2 = x2[k] + xrv[k]; t2 = (t2 > 0.f) ? t2 : 0.2f * t2; c2 += attv[k] * t2;
        float t3 = x3[k] + xrv[k]; t3 = (t3 > 0.f) ? t3 : 0.2f * t3; c3 += attv[k] * t3;
      }
#pragma unroll
      for (int off = 32; off >= 1; off >>= 1) {
        c0 += __shfl_xor(c0, off, 64);
        c1 += __shfl_xor(c1, off, 64);
        c2 += __shfl_xor(c2, off, 64);
        c3 += __shfl_xor(c3, off, 64);
      }
      float p0 = __expf(c0 - m0), p1 = __expf(c1 - m0);
      float p2 = __expf(c2 - m0), p3 = __expf(c3 - m0);
      lsum += p0 + p1 + p2 + p3;
#pragma unroll
      for (int k = 0; k < 8; k++)
        acc[k] += p0 * x0[k] + p1 * x1[k] + p2 * x2[k] + p3 * x3[k];
    }
    for (; e < e1; ++e) {
      int s0 = ssrc[e];
      uint2 q = *(const uint2*)&xl8[(size_t)s0 * 512 + base];
      float x0[8];
      f8x4(q.x, x0);
      f8x4(q.y, x0 + 4);
      float sc0 = 0.f;
#pragma unroll
      for (int k = 0; k < 8; k++) {
        float t0 = x0[k] + xrv[k];
        t0 = (t0 > 0.f) ? t0 : 0.2f * t0;
        sc0 += attv[k] * t0;
      }
#pragma unroll
      for (int off = 32; off >= 1; off >>= 1) sc0 += __shfl_xor(sc0, off, 64);
      float p0 = __expf(sc0 - m0);
      lsum += p0;
#pragma unroll
      for (int k = 0; k < 8; k++) acc[k] += p0 * x0[k];
    }
    float inv = 1.f / lsum;
    float o[8];
    float s = 0.f, ss = 0.f;
    short8 o8;
#pragma unroll
    for (int k = 0; k < 8; k++) {
      o[k] = acc[k] * inv + bias[base + k];
      s += o[k];
      ss += o[k] * o[k];
      o8[k] = f2bs(o[k]);
    }
    *(short8*)&out[(size_t)n * 512 + base] = o8;
    if (statsOut) {
#pragma unroll
      for (int off = 32; off >= 1; off >>= 1) {
        s += __shfl_xor(s, off, 64);
        ss += __shfl_xor(ss, off, 64);
      }
      if (lane == 0) { redS[wid] = s; redSS[wid] = ss; }
    }
  }
  if (statsOut) {
    __syncthreads();
    if (threadIdx.x == 0) {
      float a = redS[0] + redS[1] + redS[2] + redS[3];
      float b = redSS[0] + redSS[1] + redSS[2] + redSS[3];
      int slot = blockIdx.x & 15;
      atomicAdd(&statsOut[slot], a);
      atomicAdd(&statsOut[16 + slot], b);
    }
  }
}

// ---------- CloudGraph: 4 waves per balanced node pair (p, 95-p); 2 dims/lane ----
__global__ __launch_bounds__(256) void k_cloud(const bf16* __restrict__ g1,
                                               const float* __restrict__ ep,
                                               const float* __restrict__ lin1b,
                                               const float* __restrict__ w3,
                                               float* __restrict__ p1,
                                               float* __restrict__ p2) {
  int w = (blockIdx.x * blockDim.x + threadIdx.x) >> 6;
  int lane = threadIdx.x & 63;
  if (w >= NN * 2) return;
  int qf = w & 3;
  int pi = w >> 2;              // [0, 2304)
  int g = pi / 48, pp = pi % 48;
  int d0 = qf * 128 + lane * 2;
  float bb0 = lin1b[d0], bb1 = lin1b[d0 + 1];
  float w00 = w3[d0], w01 = w3[d0 + 1];
  float w10 = w3[512 + d0], w11 = w3[512 + d0 + 1];
  float w20 = w3[1024 + d0], w21 = w3[1024 + d0 + 1];

#pragma unroll
  for (int half = 0; half < 2; half++) {
    int p = half ? (NPG - 1 - pp) : pp;
    int n = g * NPG + p;
    int cnt = NPG - p;
    int slot0 = g * TRIU + p * NPG - (p * (p - 1)) / 2;
    unsigned int giw = *(const unsigned int*)&g1[(size_t)n * 512 + d0];
    float gi0 = s2f((short)(giw & 0xffff));
    float gi1 = s2f((short)(giw >> 16));
    float a10 = 0.f, a11 = 0.f, a20 = 0.f, a21 = 0.f;
    int e = 0;
    for (; e + 1 < cnt; e += 2) {
      float4 pa = *(const float4*)&ep[(size_t)(slot0 + e) * 4];
      float4 pb = *(const float4*)&ep[(size_t)(slot0 + e + 1) * 4];
      unsigned int gaw = *(const unsigned int*)&g1[(size_t)(n + e) * 512 + d0];
      unsigned int gbw = *(const unsigned int*)&g1[(size_t)(n + e + 1) * 512 + d0];
      float t;
      t = fmaf(pa.w, gi0 - s2f((short)(gaw & 0xffff)), bb0); a10 += fmaxf(t, 0.f);
      t = fmaf(pa.w, gi1 - s2f((short)(gaw >> 16)), bb1);    a11 += fmaxf(t, 0.f);
      t = fmaf(pb.w, gi0 - s2f((short)(gbw & 0xffff)), bb0); a10 += fmaxf(t, 0.f);
      t = fmaf(pb.w, gi1 - s2f((short)(gbw >> 16)), bb1);    a11 += fmaxf(t, 0.f);
      t = pa.x * w00 + pa.y * w10 + pa.z * w20; a20 += fmaxf(t, 0.f);
      t = pa.x * w01 + pa.y * w11 + pa.z * w21; a21 += fmaxf(t, 0.f);
      t = pb.x * w00 + pb.y * w10 + pb.z * w20; a20 += fmaxf(t, 0.f);
      t = pb.x * w01 + pb.y * w11 + pb.z * w21; a21 += fmaxf(t, 0.f);
    }
    if (e < cnt) {
      float4 pa = *(const float4*)&ep[(size_t)(slot0 + e) * 4];
      unsigned int gaw = *(const unsigned int*)&g1[(size_t)(n + e) * 512 + d0];
      float t;
      t = fmaf(pa.w, gi0 - s2f((short)(gaw & 0xffff)), bb0); a10 += fmaxf(t, 0.f);
      t = fmaf(pa.w, gi1 - s2f((short)(gaw >> 16)), bb1);    a11 += fmaxf(t, 0.f);
      t = pa.x * w00 + pa.y * w10 + pa.z * w20; a20 += fmaxf(t, 0.f);
      t = pa.x * w01 + pa.y * w11 + pa.z * w21; a21 += fmaxf(t, 0.f);
    }
    float2 o1, o2;
    o1.x = a10; o1.y = a11;
    o2.x = a20; o2.y = a21;
    *(float2*)&p1[(size_t)n * 512 + d0] = o1;
    *(float2*)&p2[(size_t)n * 512 + d0] = o2;
  }
}

// ---------- fused cloud epilogue: ln_row(p1) + bn(p2) + fuse -> s_bf ----------
// Also zeroes colsum2/colsq2 (1024 floats) for the final GEMM's column stats.
__global__ __launch_bounds__(256) void k_cloud_epi(
    const float* __restrict__ p1, const float* __restrict__ p2,
    const bf16* __restrict__ h_bf, const bf16* __restrict__ xg_bf,
    const float* __restrict__ colsum, const float* __restrict__ colsq,
    const float* __restrict__ lng, const float* __restrict__ lnb,
    const float* __restrict__ bng, const float* __restrict__ bnb,
    bf16* __restrict__ s_bf, float* __restrict__ zptr) {
  if (blockIdx.x == 0) {
    for (int i = threadIdx.x; i < 1024; i += 256) zptr[i] = 0.f;
  }
  int wave = (blockIdx.x * blockDim.x + threadIdx.x) >> 6;
  int lane = threadIdx.x & 63;
  if (wave >= NN) return;
  int n = wave;
  size_t rb = (size_t)n * 512 + lane * 8;
  int base = lane * 8;
  float v[8];
  float s = 0.f;
#pragma unroll
  for (int k = 0; k < 8; k++) {
    v[k] = p1[rb + k];
    s += v[k];
  }
#pragma unroll
  for (int off = 32; off >= 1; off >>= 1) s += __shfl_xor(s, off, 64);
  float mu = s * (1.f / 512.f);
  float ss = 0.f;
#pragma unroll
  for (int k = 0; k < 8; k++) {
    float t = v[k] - mu;
    ss += t * t;
  }
#pragma unroll
  for (int off = 32; off >= 1; off >>= 1) ss += __shfl_xor(ss, off, 64);
  float inv = 1.f / sqrtf(ss * (1.f / 512.f) + 1e-5f);
  short8 hb = *(const short8*)&h_bf[rb];
  short8 xb = *(const short8*)&xg_bf[rb];
  short8 o8;
#pragma unroll
  for (int k = 0; k < 8; k++) {
    int d = base + k;
    float ln1 = (v[k] - mu) * inv * lng[d] + lnb[d];
    float cmu = colsum[d] * (1.f / NN);
    float cvar = colsq[d] * (1.f / NN) - cmu * cmu;
    float cinv = 1.f / sqrtf(fmaxf(cvar, 0.f) + 1e-5f);
    float bnv = (p2[rb + k] - cmu) * cinv * bng[d] + bnb[d];
    float out = 2.f * s2f(hb[k]) + s2f(xb[k]) + ln1 + bnv;
    o8[k] = f2bs(out);
  }
  *(short8*)&s_bf[rb] = o8;
}

// ---------- column (batchnorm) stats (used for p2 only) ----------
__global__ void k_col_reduce(const float* __restrict__ x, float* colsum, float* colsq) {
  int r0 = blockIdx.x * 128;
  int c0 = threadIdx.x;
  float s0 = 0.f, q0 = 0.f, s1 = 0.f, q1 = 0.f;
  for (int r = r0; r < r0 + 128; ++r) {
    float v = x[(size_t)r * 512 + c0];
    s0 += v;
    q0 += v * v;
    float w = x[(size_t)r * 512 + c0 + 256];
    s1 += w;
    q1 += w * w;
  }
  atomicAdd(&colsum[c0], s0);
  atomicAdd(&colsq[c0], q0);
  atomicAdd(&colsum[c0 + 256], s1);
  atomicAdd(&colsq[c0 + 256], q1);
}
__global__ void k_bn_out(const float* __restrict__ y, const float* __restrict__ colsum,
                         const float* __restrict__ colsq, const float* __restrict__ g,
                         const float* __restrict__ b, float* __restrict__ out) {
  int i = blockIdx.x * blockDim.x + threadIdx.x;
  if (i >= NN * DD) return;
  int d = i & 511;
  float mu = colsum[d] * (1.f / NN);
  float var = colsq[d] * (1.f / NN) - mu * mu;
  float inv = 1.f / sqrtf(fmaxf(var, 0.f) + 1e-5f);
  out[i] = (y[i] - mu) * inv * g[d] + b[d];
}

extern "C" void kernel_launch(void* const* d_in, const int* in_sizes, int n_in,
                              void* d_out, int out_size, void* d_ws, size_t ws_size,
                              hipStream_t stream) {
  const float* x = (const float*)d_in[0];
  const int* ei = (const int*)d_in[1];
  const float* xyz = (const float*)d_in[3];
  const float* x_proj_w = (const float*)d_in[5];
  const float* x_proj_b = (const float*)d_in[6];
  const float* gat_wl = (const float*)d_in[7];
  const float* gat_bl = (const float*)d_in[8];
  const float* gat_wr = (const float*)d_in[9];
  const float* gat_br = (const float*)d_in[10];
  const float* gat_att = (const float*)d_in[11];
  const float* gat_bias = (const float*)d_in[12];
  const float* gat_ln_g = (const float*)d_in[13];
  const float* gat_ln_b = (const float*)d_in[14];
  const float* cg_xyz_w = (const float*)d_in[15];
  const float* cg_bn_g = (const float*)d_in[16];
  const float* cg_bn_b = (const float*)d_in[17];
  const float* cg_lin1_w = (const float*)d_in[18];
  const float* cg_lin1_b = (const float*)d_in[19];
  const float* cg_ln_g = (const float*)d_in[20];
  const float* cg_ln_b = (const float*)d_in[21];
  const float* lin_w = (const float*)d_in[22];
  const float* lin_b = (const float*)d_in[23];
  const float* bn_g = (const float*)d_in[24];
  const float* bn_b = (const float*)d_in[25];

  const size_t ND = (size_t)NN * DD;
  char* w = (char*)d_ws;
  float* p1 = (float*)w;       w += ND * 4;  // alias: final y
  float* p2 = (float*)w;       w += ND * 4;
  bf16* h_bf = (bf16*)w;       w += ND * 2;  // alias: s_bf (after cloud GEMM)
  bf16* xg_bf = (bf16*)w;      w += ND * 2;
  bf16* g1_bf = (bf16*)w;      w += ND * 2;
  bf16* xr_bf = (bf16*)w;      w += ND * 2;
  unsigned char* xl_f8 = (unsigned char*)w; w += ND;
  bf16* Wt = (bf16*)w;         w += (size_t)14 * NK * 2;
  float* eparam = (float*)w;   w += (size_t)BG * TRIU * 16;
  int* counts = (int*)w;       w += NN * 4;
  int* offs = (int*)w;         w += (NN + 4) * 4;
  int* cursor = (int*)w;       w += NN * 4;
  int* ssrc = (int*)w;         w += EREAL * 4;
  float* statsAll = (float*)w; w += 5 * 32 * 4;
  float* colsum = (float*)w;   w += 512 * 4;
  float* colsq = (float*)w;    w += 512 * 4;
  float* colsum2 = (float*)w;  w += 512 * 4;
  float* colsq2 = (float*)w;   w += 512 * 4;
  float* y = p1;
  bf16* s_bf = h_bf;

  const int TPB = 256;
  const int ND_BLK = (int)((ND + TPB - 1) / TPB);

  k_wt<<<dim3(16, 16, 14), TPB, 0, stream>>>(gat_wl, gat_wr, cg_lin1_w, lin_w, Wt,
                                             counts, statsAll);
  k_xproj<<<ND_BLK, TPB, 0, stream>>>(x, x_proj_w, x_proj_b, ei, xyz, h_bf,
                                      counts, eparam);
  k_scan<<<1, 256, 0, stream>>>(counts, offs, cursor);
  k_scatter<<<(EREAL + TPB - 1) / TPB, TPB, 0, stream>>>(ei, cursor, ssrc);

  for (int l = 0; l < NLAYER; l++) {
    const bf16* A = (l == 0) ? h_bf : xg_bf;
    const float* sIn = (l > 0) ? statsAll + 32 * (l - 1) : nullptr;
    const float* lg = (l > 0) ? gat_ln_g + (l - 1) * DD : nullptr;
    const float* lb = (l > 0) ? gat_ln_b + (l - 1) * DD : nullptr;
    k_gemm<<<dim3(36, 8, 2), TPB, 0, stream>>>(
        A, Wt + (size_t)l * NK, Wt + (size_t)(6 + l) * NK,
        gat_bl + l * DD, gat_br + l * DD, nullptr, nullptr, nullptr, xr_bf,
        xl_f8, nullptr, sIn, lg, lb, nullptr, 0, nullptr, nullptr);
    float* sOut = (l < NLAYER - 1) ? statsAll + 32 * l : nullptr;
    k_gat_edge<<<NN / 4, TPB, 0, stream>>>(xl_f8, xr_bf, gat_att + l * DD,
                                           gat_bias + l * DD, offs, ssrc,
                                           xg_bf, sOut);
  }

  // CloudGraph: g1 = h @ cg_lin1_w (no bias), bf16 out; zero colsum for p2 BN
  k_gemm<<<dim3(36, 8, 1), TPB, 0, stream>>>(
      h_bf, Wt + (size_t)12 * NK, Wt + (size_t)12 * NK, nullptr, nullptr,
      nullptr, nullptr, g1_bf, g1_bf, nullptr, nullptr, nullptr, nullptr, nullptr,
      colsum, 1024, nullptr, nullptr);
  k_cloud<<<NN / 2, TPB, 0, stream>>>(g1_bf, eparam, cg_lin1_b, cg_xyz_w, p1, p2);
  k_col_reduce<<<36, 256, 0, stream>>>(p2, colsum, colsq);
  k_cloud_epi<<<NN / 4, TPB, 0, stream>>>(p1, p2, h_bf, xg_bf, colsum, colsq,
                                          cg_ln_g, cg_ln_b, cg_bn_g, cg_bn_b,
                                          s_bf, colsum2);

  // final: y = s @ lin_w + lin_b (fp32) with fused column stats -> bn_out
  k_gemm<<<dim3(36, 8, 1), TPB, 0, stream>>>(
      s_bf, Wt + (size_t)13 * NK, Wt + (size_t)13 * NK, lin_b, lin_b,
      y, y, nullptr, nullptr, nullptr, nullptr, nullptr, nullptr, nullptr,
      nullptr, 0, colsum2, colsq2);
  k_bn_out<<<ND_BLK, TPB, 0, stream>>>(y, colsum2, colsq2, bn_g, bn_b,
                                       (float*)d_out);
}